// Round 2
// 891.164 us; speedup vs baseline: 1.0800x; 1.0800x over previous
//
#include <hip/hip_runtime.h>
#include <math.h>

typedef unsigned int u32;
typedef unsigned long long u64;
typedef unsigned short u16t;

#define SD   512
#define EE   8
#define DH   64
#define SDSQ (512*512)
#define LDSW 72   // padded LDS row stride in bf16 elems (144 B) — used by k_attn/k_out staging

typedef __attribute__((ext_vector_type(8))) short bfrag8;
typedef __attribute__((ext_vector_type(4))) float f32x4;
typedef __attribute__((ext_vector_type(8))) unsigned short u16x8;

typedef const __attribute__((address_space(1))) void gas_void;
typedef __attribute__((address_space(3))) void las_void;

#define MFMA_B16(a,b,c) __builtin_amdgcn_mfma_f32_16x16x32_bf16((a),(b),(c),0,0,0)

__device__ __forceinline__ u32 rotl32(u32 x, int r){ return (x<<r)|(x>>(32-r)); }

__device__ __forceinline__ u16t bf_hi(float a){
  u32 x; __builtin_memcpy(&x,&a,4);
  u32 r = x + 0x7fffu + ((x>>16)&1u);
  return (u16t)(r>>16);
}
__device__ __forceinline__ float bf_f(u16t h){
  u32 x = ((u32)h)<<16; float f; __builtin_memcpy(&f,&x,4); return f;
}
__device__ __forceinline__ void split2(float a, u16t& h, u16t& l){
  h = bf_hi(a);
  l = bf_hi(a - bf_f(h));
}

// async global->LDS, 16B per lane; LDS dest is wave-uniform base + lane*16
__device__ __forceinline__ void gload16(const u16t* g, u16t* l){
  __builtin_amdgcn_global_load_lds((gas_void*)g, (las_void*)l, 16, 0, 0);
}

// threefry2x32, key = (0, 42)
__device__ __forceinline__ void threefry_0_42(u32 x0, u32 x1, u32& o0, u32& o1){
  const u32 k0=0u, k1=42u;
  const u32 ks2 = k0 ^ k1 ^ 0x1BD11BDAu;
  const int R0[4]={13,15,26,6}, R1[4]={17,29,16,24};
  x0 += k0; x1 += k1;
  #pragma unroll
  for(int r=0;r<4;r++){ x0+=x1; x1=rotl32(x1,R0[r]); x1^=x0; }
  x0+=k1; x1+=ks2+1u;
  #pragma unroll
  for(int r=0;r<4;r++){ x0+=x1; x1=rotl32(x1,R1[r]); x1^=x0; }
  x0+=ks2; x1+=k0+2u;
  #pragma unroll
  for(int r=0;r<4;r++){ x0+=x1; x1=rotl32(x1,R0[r]); x1^=x0; }
  x0+=k0; x1+=k1+3u;
  #pragma unroll
  for(int r=0;r<4;r++){ x0+=x1; x1=rotl32(x1,R1[r]); x1^=x0; }
  x0+=k1; x1+=ks2+4u;
  #pragma unroll
  for(int r=0;r<4;r++){ x0+=x1; x1=rotl32(x1,R0[r]); x1^=x0; }
  x0+=ks2; x1+=k0+5u;
  o0 = x0; o1 = x1;
}

__device__ double erfinv64(double x){
  double w = -log((1.0 - x) * (1.0 + x));
  double p;
  if (w < 5.0){
    w = w - 2.5;
    p = 2.81022636e-08;
    p = 3.43273939e-07 + p*w;
    p = -3.5233877e-06 + p*w;
    p = -4.39150654e-06 + p*w;
    p = 0.00021858087  + p*w;
    p = -0.00125372503 + p*w;
    p = -0.00417768164 + p*w;
    p = 0.246640727    + p*w;
    p = 1.50140941     + p*w;
  } else {
    w = sqrt(w) - 3.0;
    p = -0.000200214257;
    p = 0.000100950558 + p*w;
    p = 0.00134934322  + p*w;
    p = -0.00367342844 + p*w;
    p = 0.00573950773  + p*w;
    p = -0.0076224613  + p*w;
    p = 0.00943887047  + p*w;
    p = 1.00167406     + p*w;
    p = 2.83297682     + p*w;
  }
  double r = p * x;
  #pragma unroll
  for (int it=0; it<2; ++it){
    double e = erf(r) - x;
    r -= e / (1.1283791670955126 * exp(-r*r));
  }
  return r;
}

__device__ double jax_noise_part32(int i){
  u32 o0, o1;
  threefry_0_42(0u, (u32)i, o0, o1);
  u32 bits = o0 ^ o1;
  u32 fb = (bits >> 9) | 0x3f800000u;
  float f; __builtin_memcpy(&f, &fb, 4);
  f -= 1.0f;
  u32 lob = 0xBF7FFFFFu;
  float lo; __builtin_memcpy(&lo, &lob, 4);
  float t = f * 2.0f;
  float u = t + lo;
  u = fmaxf(u, lo);
  return 1.4142135623730951 * erfinv64((double)u);
}

// ---------- P0a: fp32 -> bf16 hi/lo (optionally NaN-clean), layout-preserving ----------
__global__ __launch_bounds__(256) void k_cvt_x(
  const float* __restrict__ src, u16t* __restrict__ dh, u16t* __restrict__ dl, int clean)
{
  const int n4 = 32*SDSQ/4;
  int i = blockIdx.x*256 + threadIdx.x;
  if (i >= n4) return;
  float4 r = ((const float4*)src)[i];
  float a[4] = {r.x, r.y, r.z, r.w};
  if (clean){
    #pragma unroll
    for (int u=0;u<4;u++) if (isnan(a[u])) a[u] = 0.f;
  }
  u16t h[4], l[4];
  #pragma unroll
  for (int u=0;u<4;u++) split2(a[u], h[u], l[u]);
  ((ushort4*)dh)[i] = make_ushort4(h[0],h[1],h[2],h[3]);
  ((ushort4*)dl)[i] = make_ushort4(l[0],l[1],l[2],l[3]);
}

// ---------- P0b: W[e][k][f] fp32 -> Wt[e][f][k] bf16 hi/lo (transpose + split) ----------
__global__ __launch_bounds__(256) void k_cvt_w(
  const float* __restrict__ W, u16t* __restrict__ th, u16t* __restrict__ tl)
{
  __shared__ u16t Th[64*LDSW], Tl[64*LDSW];
  int e = blockIdx.z;
  int k0 = blockIdx.y*64, f0 = blockIdx.x*64;
  int tid = threadIdx.x;
  int r = tid>>2, c4 = (tid&3)*16;
  const float* Wp = W + (size_t)e*SDSQ + (size_t)(k0+r)*SD + f0 + c4;
  #pragma unroll
  for (int i=0;i<4;i++){
    float4 rv = *(const float4*)(Wp + 4*i);
    float a[4]={rv.x,rv.y,rv.z,rv.w};
    #pragma unroll
    for (int u=0;u<4;u++){
      u16t h,l; split2(a[u],h,l);
      Th[(c4+4*i+u)*LDSW + r] = h;
      Tl[(c4+4*i+u)*LDSW + r] = l;
    }
  }
  __syncthreads();
  u16t* dh = th + (size_t)e*SDSQ + (size_t)(f0+r)*SD + k0 + c4;
  u16t* dl = tl + (size_t)e*SDSQ + (size_t)(f0+r)*SD + k0 + c4;
  *(u16x8*)dh     = *(const u16x8*)&Th[r*LDSW + c4];
  *(u16x8*)(dh+8) = *(const u16x8*)&Th[r*LDSW + c4 + 8];
  *(u16x8*)dl     = *(const u16x8*)&Tl[r*LDSW + c4];
  *(u16x8*)(dl+8) = *(const u16x8*)&Tl[r*LDSW + c4 + 8];
}

// ---------- K1: xs[b][d] = sum_s nan_to_zero(q[b][s][d])  (f64 accum) ----------
__global__ void k_xs(const float* __restrict__ q, double* __restrict__ xs){
  int b = blockIdx.x, d = threadIdx.x;
  const float* p = q + (size_t)b*SDSQ + d;
  double acc = 0.0;
  for (int s=0; s<SD; ++s){
    float f = p[(size_t)s*SD];
    if (!isnan(f)) acc += (double)f;
  }
  xs[b*SD + d] = acc;
}

// ---------- K2: gating in f64 ----------
__global__ __launch_bounds__(256) void k_gate(
    const double* __restrict__ xs, const float* __restrict__ wg,
    const float* __restrict__ wn, int* __restrict__ tk_idx,
    float* __restrict__ tk_gates, float* __restrict__ out_loss)
{
  __shared__ double cl_s[256], sd_s[256], nz_s[256], pr_s[256];
  __shared__ double thrI_s[32], thrO_s[32], g0_s[32], g1_s[32];
  __shared__ int i0_s[32], i1_s[32];
  int tid = threadIdx.x;
  int b = tid >> 3, e = tid & 7;
  double c=0.0, n=0.0;
  const double* xr = xs + b*SD;
  for (int d=0; d<SD; ++d){
    double x = xr[d];
    c += x * (double)wg[d*EE + e];
    n += x * (double)wn[d*EE + e];
  }
  double sp = fmax(n, 0.0) + log1p(exp(-fabs(n)));
  double sdv = sp + 0.01;
  double nz = c + jax_noise_part32(tid) * sdv;
  cl_s[tid]=c; sd_s[tid]=sdv; nz_s[tid]=nz;
  __syncthreads();
  if (tid < 32){
    int bb = tid;
    double v0=-INFINITY,v1=-INFINITY,v2=-INFINITY; int i0=0,i1=0;
    for (int ee=0; ee<8; ++ee){
      double vv = nz_s[bb*8+ee];
      if (vv > v0){ v2=v1; v1=v0;i1=i0; v0=vv;i0=ee; }
      else if (vv > v1){ v2=v1; v1=vv;i1=ee; }
      else if (vv > v2){ v2=vv; }
    }
    double e1 = exp(v1 - v0);
    double s = 1.0 + e1;
    double g0 = 1.0/s + 1e-9, g1 = e1/s + 1e-9;
    tk_idx[bb*2+0]=i0; tk_idx[bb*2+1]=i1;
    tk_gates[bb*2+0]=(float)g0; tk_gates[bb*2+1]=(float)g1;
    i0_s[bb]=i0; i1_s[bb]=i1; g0_s[bb]=g0; g1_s[bb]=g1;
    thrI_s[bb]=v2; thrO_s[bb]=v1;
  }
  __syncthreads();
  {
    double thrI = thrI_s[b], thrO = thrO_s[b];
    bool isin = nz_s[tid] > thrI;
    double t = (cl_s[tid] - (isin ? thrI : thrO)) / sd_s[tid];
    pr_s[tid] = 0.5 * (1.0 + erf(t * 0.7071067811865476));
  }
  __syncthreads();
  if (tid == 0){
    double imp[8], ld[8];
    for (int i=0;i<8;i++){ imp[i]=0.0; ld[i]=0.0; }
    for (int bb=0; bb<32; ++bb){
      imp[i0_s[bb]] += g0_s[bb];
      imp[i1_s[bb]] += g1_s[bb];
    }
    for (int i=0;i<256;i++) ld[i&7] += pr_s[i];
    double loss = 0.0;
    for (int a=0;a<2;a++){
      double* arr = a ? ld : imp;
      double mu=0.0; for(int i=0;i<8;i++) mu += arr[i]; mu *= 0.125;
      double var=0.0; for(int i=0;i<8;i++){ double dd=arr[i]-mu; var += dd*dd; }
      var *= (1.0/7.0);
      loss += var / (mu*mu + 1e-10);
    }
    loss *= 0.01;
    out_loss[0] = (float)loss;
  }
}

// ---------- K3: MFMA bf16x3 GEMM  Y = X @ W[e] + bias[e] ----------
// 128x128 tile, BK=64, 4 waves (2x2), global_load_lds staging with XOR chunk swizzle.
// Operands pre-split (hi/lo bf16) and W pre-transposed to [e][f][k] by P0a/P0b.
__global__ __launch_bounds__(256) void k_proj(
  const u16t* __restrict__ qh, const u16t* __restrict__ ql,
  const u16t* __restrict__ kh, const u16t* __restrict__ kl,
  const u16t* __restrict__ vh, const u16t* __restrict__ vl,
  const u16t* __restrict__ wqh, const u16t* __restrict__ wql,
  const u16t* __restrict__ wkh, const u16t* __restrict__ wkl,
  const u16t* __restrict__ wvh, const u16t* __restrict__ wvl,
  const float* __restrict__ bq, const float* __restrict__ bk, const float* __restrict__ bv,
  const int* __restrict__ tk_idx, int pair0,
  float* __restrict__ Qb, float* __restrict__ Kb, float* __restrict__ Vb)
{
  __shared__ __align__(16) u16t Ah[128*64], Al[128*64], Bh[128*64], Bl[128*64];
  int z = blockIdx.z;
  int lp = z/3, m = z - lp*3;
  int gp = pair0 + lp;
  int b = gp >> 1;
  int e = tk_idx[gp] & 7;
  const u16t *Xh, *Xl, *Wh, *Wl; const float* bias; float* Y;
  if (m==0){ Xh=qh; Xl=ql; Wh=wqh; Wl=wql; bias=bq; Y=Qb; }
  else if (m==1){ Xh=kh; Xl=kl; Wh=wkh; Wl=wkl; bias=bk; Y=Kb; }
  else { Xh=vh; Xl=vl; Wh=wvh; Wl=wvl; bias=bv; Y=Vb; }
  Xh += (size_t)b*SDSQ; Xl += (size_t)b*SDSQ;
  Wh += (size_t)e*SDSQ; Wl += (size_t)e*SDSQ;
  bias += e*SD; Y += (size_t)lp*SDSQ;

  int tid = threadIdx.x, w = tid>>6, lane = tid&63;
  int q16 = lane&15, quad = lane>>4;
  int wm = w>>1, wn = w&1;
  int s0 = blockIdx.y*128, f0 = blockIdx.x*128;
  int row8 = lane>>3, cc = lane&7;
  int soff = (cc ^ row8)*8;          // inverse-swizzled source chunk (rule #21)
  int sw = q16 & 7;                  // read-side swizzle key (= row&7 of frag row)

  f32x4 acc[4][4];
  #pragma unroll
  for (int i=0;i<4;i++)
    #pragma unroll
    for (int j=0;j<4;j++) acc[i][j] = (f32x4){0.f,0.f,0.f,0.f};

  for (int k0=0;k0<SD;k0+=64){
    // stage 64KB: per wave 4 issues x 4 buffers, each issue = 8 rows x 128B, linear dest
    #pragma unroll
    for (int t=0;t<4;t++){
      int br = w*32 + t*8;
      int gr = br + row8;
      size_t ga = (size_t)(s0+gr)*SD + k0 + soff;
      size_t gbo = (size_t)(f0+gr)*SD + k0 + soff;
      gload16(Xh + ga,  &Ah[br*64]);
      gload16(Xl + ga,  &Al[br*64]);
      gload16(Wh + gbo, &Bh[br*64]);
      gload16(Wl + gbo, &Bl[br*64]);
    }
    __syncthreads();
    #pragma unroll
    for (int kk=0;kk<2;kk++){
      int ch = kk*4 + quad;
      int co = (ch ^ sw)*8;          // swizzled read chunk
      bfrag8 aH[4], aL[4], bH[4], bL[4];
      #pragma unroll
      for (int i=0;i<4;i++){
        int ra = wm*64 + i*16 + q16;
        int rb = wn*64 + i*16 + q16;
        aH[i] = *(const bfrag8*)&Ah[ra*64 + co];
        aL[i] = *(const bfrag8*)&Al[ra*64 + co];
        bH[i] = *(const bfrag8*)&Bh[rb*64 + co];
        bL[i] = *(const bfrag8*)&Bl[rb*64 + co];
      }
      #pragma unroll
      for (int i=0;i<4;i++)
        #pragma unroll
        for (int j=0;j<4;j++){
          acc[i][j] = MFMA_B16(aH[i], bH[j], acc[i][j]);
          acc[i][j] = MFMA_B16(aH[i], bL[j], acc[i][j]);
          acc[i][j] = MFMA_B16(aL[i], bH[j], acc[i][j]);
        }
    }
    __syncthreads();
  }
  #pragma unroll
  for (int i=0;i<4;i++){
    #pragma unroll
    for (int j=0;j<4;j++){
      int f = f0 + wn*64 + j*16 + q16;
      float bb = bias[f];
      #pragma unroll
      for (int rr=0;rr<4;rr++){
        int s = s0 + wm*64 + i*16 + quad*4 + rr;
        Y[(size_t)s*SD + f] = acc[i][j][rr] + bb;
      }
    }
  }
}

// ---------- K4: MFMA flash attention per (pair, head, q-tile 64) ----------
__global__ __launch_bounds__(256) void k_attn(
  const float* __restrict__ Qb, const float* __restrict__ Kb, const float* __restrict__ Vb,
  float* __restrict__ Cb)
{
  __shared__ __align__(16) u16t QH[64*LDSW], QL[64*LDSW];   // [q][d]
  __shared__ __align__(16) u16t KH[64*LDSW], KL[64*LDSW];   // [key][d]
  __shared__ __align__(16) u16t VTH[64*LDSW], VTL[64*LDSW]; // transposed: [dh][key]
  __shared__ __align__(16) u16t PS[64*LDSW];                // [q][key]
  int lp = blockIdx.z, h = blockIdx.y, qt = blockIdx.x;
  int tid = threadIdx.x;
  int w = tid>>6, lane = tid&63, q16 = lane&15, quad = lane>>4;
  int s0 = qt*64;
  const size_t base = (size_t)lp*SDSQ + h*DH;
  int r = tid>>2, cb = (tid&3)*4;

  // stage Q once
  #pragma unroll
  for (int i=0;i<4;i++){
    int col = cb + 16*i;
    float4 ra = *(const float4*)(Qb + base + (size_t)(s0+r)*SD + col);
    float a4[4]={ra.x,ra.y,ra.z,ra.w};
    u16t hh[4], ll[4];
    #pragma unroll
    for (int u=0;u<4;u++) split2(a4[u], hh[u], ll[u]);
    *(ushort4*)&QH[r*LDSW+col] = make_ushort4(hh[0],hh[1],hh[2],hh[3]);
    *(ushort4*)&QL[r*LDSW+col] = make_ushort4(ll[0],ll[1],ll[2],ll[3]);
  }

  float m_row[4], l_row[4];
  f32x4 ctx[4];
  #pragma unroll
  for (int rr=0;rr<4;rr++){ m_row[rr]=-INFINITY; l_row[rr]=0.f; }
  #pragma unroll
  for (int nt=0;nt<4;nt++) ctx[nt] = (f32x4){0.f,0.f,0.f,0.f};

  for (int kt=0; kt<8; ++kt){
    // stage K
    #pragma unroll
    for (int i=0;i<4;i++){
      int col = cb + 16*i;
      float4 rk = *(const float4*)(Kb + base + (size_t)(kt*64+r)*SD + col);
      float a4[4]={rk.x,rk.y,rk.z,rk.w};
      u16t hh[4], ll[4];
      #pragma unroll
      for (int u=0;u<4;u++) split2(a4[u], hh[u], ll[u]);
      *(ushort4*)&KH[r*LDSW+col] = make_ushort4(hh[0],hh[1],hh[2],hh[3]);
      *(ushort4*)&KL[r*LDSW+col] = make_ushort4(ll[0],ll[1],ll[2],ll[3]);
    }
    // stage V transposed: V[key][dh] -> VT[dh][key]
    #pragma unroll
    for (int i=0;i<4;i++){
      int dh = cb + 16*i;
      float4 rv = *(const float4*)(Vb + base + (size_t)(kt*64+r)*SD + dh);
      float a4[4]={rv.x,rv.y,rv.z,rv.w};
      #pragma unroll
      for (int u=0;u<4;u++){
        u16t hh, ll; split2(a4[u], hh, ll);
        VTH[(dh+u)*LDSW + r] = hh;
        VTL[(dh+u)*LDSW + r] = ll;
      }
    }
    __syncthreads();

    // scores = Q K^T (bf16x3)
    f32x4 sc[4];
    #pragma unroll
    for (int nt=0;nt<4;nt++) sc[nt] = (f32x4){0.f,0.f,0.f,0.f};
    #pragma unroll
    for (int kk=0;kk<2;kk++){
      bfrag8 aH = *(const bfrag8*)&QH[(w*16+q16)*LDSW + kk*32 + quad*8];
      bfrag8 aL = *(const bfrag8*)&QL[(w*16+q16)*LDSW + kk*32 + quad*8];
      #pragma unroll
      for (int nt=0;nt<4;nt++){
        bfrag8 bH = *(const bfrag8*)&KH[(nt*16+q16)*LDSW + kk*32 + quad*8];
        bfrag8 bL = *(const bfrag8*)&KL[(nt*16+q16)*LDSW + kk*32 + quad*8];
        sc[nt] = MFMA_B16(aH,bH,sc[nt]);
        sc[nt] = MFMA_B16(aH,bL,sc[nt]);
        sc[nt] = MFMA_B16(aL,bH,sc[nt]);
      }
    }
    #pragma unroll
    for (int nt=0;nt<4;nt++)
      #pragma unroll
      for (int rr=0;rr<4;rr++) sc[nt][rr] *= 0.125f;

    float alpha[4];
    #pragma unroll
    for (int rr=0;rr<4;rr++){
      float mx = sc[0][rr];
      #pragma unroll
      for (int nt=1;nt<4;nt++) mx = fmaxf(mx, sc[nt][rr]);
      mx = fmaxf(mx, __shfl_xor(mx, 1));
      mx = fmaxf(mx, __shfl_xor(mx, 2));
      mx = fmaxf(mx, __shfl_xor(mx, 4));
      mx = fmaxf(mx, __shfl_xor(mx, 8));
      float nm = fmaxf(m_row[rr], mx);
      alpha[rr] = expf(m_row[rr] - nm);
      m_row[rr] = nm;
    }
    #pragma unroll
    for (int rr=0;rr<4;rr++){
      float S = 0.f;
      #pragma unroll
      for (int nt=0;nt<4;nt++){
        float p = expf(sc[nt][rr] - m_row[rr]);
        sc[nt][rr] = p;
        S += p;
      }
      S += __shfl_xor(S, 1);
      S += __shfl_xor(S, 2);
      S += __shfl_xor(S, 4);
      S += __shfl_xor(S, 8);
      l_row[rr] = l_row[rr]*alpha[rr] + S;
      #pragma unroll
      for (int nt=0;nt<4;nt++) ctx[nt][rr] *= alpha[rr];
    }
    #pragma unroll
    for (int nt=0;nt<4;nt++)
      #pragma unroll
      for (int rr=0;rr<4;rr++)
        PS[(w*16 + quad*4 + rr)*LDSW + nt*16 + q16] = bf_hi(sc[nt][rr]);
    __syncthreads();

    // ctx += P V  (P plain bf16, V bf16x2)
    #pragma unroll
    for (int kk2=0;kk2<2;kk2++){
      bfrag8 aP = *(const bfrag8*)&PS[(w*16+q16)*LDSW + kk2*32 + quad*8];
      #pragma unroll
      for (int nt=0;nt<4;nt++){
        bfrag8 vH = *(const bfrag8*)&VTH[(nt*16+q16)*LDSW + kk2*32 + quad*8];
        bfrag8 vL = *(const bfrag8*)&VTL[(nt*16+q16)*LDSW + kk2*32 + quad*8];
        ctx[nt] = MFMA_B16(aP,vH,ctx[nt]);
        ctx[nt] = MFMA_B16(aP,vL,ctx[nt]);
      }
    }
    __syncthreads();
  }
  #pragma unroll
  for (int rr=0;rr<4;rr++){
    float inv = 1.f / l_row[rr];
    #pragma unroll
    for (int nt=0;nt<4;nt++){
      int s = s0 + w*16 + quad*4 + rr;
      Cb[base + (size_t)s*SD + nt*16 + q16] = ctx[nt][rr]*inv;
    }
  }
}

// ---------- K5: MFMA bf16x3: out = log(sum_j g_j * exp(ctx_j @ Wo[e_j] + bo[e_j])) ----------
// B operand comes pre-transposed/pre-split: Wot[e][f][k] hi/lo (plain copies, no scatter)
__global__ __launch_bounds__(256) void k_out(
  const float* __restrict__ Cb, const u16t* __restrict__ Wth, const u16t* __restrict__ Wtl,
  const float* __restrict__ bo, const int* __restrict__ tk_idx,
  const float* __restrict__ tk_gates, int pair0, float* __restrict__ out)
{
  __shared__ __align__(16) u16t Ah[64*LDSW], Al[64*LDSW];
  __shared__ __align__(16) u16t Bh[64*LDSW], Bl[64*LDSW];   // [f][k]
  int lb = blockIdx.z;
  int gb = (pair0 >> 1) + lb;
  int tid = threadIdx.x;
  int w = tid>>6, lane = tid&63, q16 = lane&15, quad = lane>>4;
  int s0 = blockIdx.y*64, f0 = blockIdx.x*64;
  int r = tid>>2, cb = (tid&3)*4, kc = (tid&3)*16;

  f32x4 acc2[2][4];
  #pragma unroll
  for (int j=0;j<2;j++)
    #pragma unroll
    for (int nt=0;nt<4;nt++) acc2[j][nt] = (f32x4){0.f,0.f,0.f,0.f};

  for (int j=0;j<2;++j){
    int e = tk_idx[pair0 + lb*2 + j] & 7;
    const float* A = Cb + (size_t)(lb*2+j)*SDSQ;
    const u16t* WH = Wth + (size_t)e*SDSQ;
    const u16t* WL = Wtl + (size_t)e*SDSQ;
    for (int k0=0;k0<SD;k0+=64){
      #pragma unroll
      for (int i=0;i<4;i++){
        int col = cb + 16*i;
        float4 ra = *(const float4*)(A + (size_t)(s0+r)*SD + k0 + col);
        float a4[4]={ra.x,ra.y,ra.z,ra.w};
        u16t hh[4], ll[4];
        #pragma unroll
        for (int u=0;u<4;u++) split2(a4[u], hh[u], ll[u]);
        *(ushort4*)&Ah[r*LDSW+col] = make_ushort4(hh[0],hh[1],hh[2],hh[3]);
        *(ushort4*)&Al[r*LDSW+col] = make_ushort4(ll[0],ll[1],ll[2],ll[3]);
      }
      {
        const u16t* ph = WH + (size_t)(f0+r)*SD + k0 + kc;
        const u16t* pl = WL + (size_t)(f0+r)*SD + k0 + kc;
        *(u16x8*)&Bh[r*LDSW + kc]     = *(const u16x8*)ph;
        *(u16x8*)&Bh[r*LDSW + kc + 8] = *(const u16x8*)(ph+8);
        *(u16x8*)&Bl[r*LDSW + kc]     = *(const u16x8*)pl;
        *(u16x8*)&Bl[r*LDSW + kc + 8] = *(const u16x8*)(pl+8);
      }
      __syncthreads();
      #pragma unroll
      for (int kk=0;kk<2;kk++){
        bfrag8 aH = *(const bfrag8*)&Ah[(w*16+q16)*LDSW + kk*32 + quad*8];
        bfrag8 aL = *(const bfrag8*)&Al[(w*16+q16)*LDSW + kk*32 + quad*8];
        #pragma unroll
        for (int nt=0;nt<4;nt++){
          bfrag8 bH = *(const bfrag8*)&Bh[(nt*16+q16)*LDSW + kk*32 + quad*8];
          bfrag8 bL = *(const bfrag8*)&Bl[(nt*16+q16)*LDSW + kk*32 + quad*8];
          acc2[j][nt] = MFMA_B16(aH,bH,acc2[j][nt]);
          acc2[j][nt] = MFMA_B16(aH,bL,acc2[j][nt]);
          acc2[j][nt] = MFMA_B16(aL,bH,acc2[j][nt]);
        }
      }
      __syncthreads();
    }
  }
  int e0 = tk_idx[pair0 + lb*2 + 0] & 7, e1 = tk_idx[pair0 + lb*2 + 1] & 7;
  float g0 = tk_gates[pair0 + lb*2 + 0], g1 = tk_gates[pair0 + lb*2 + 1];
  #pragma unroll
  for (int nt=0;nt<4;nt++){
    #pragma unroll
    for (int rr=0;rr<4;rr++){
      int s = s0 + w*16 + quad*4 + rr;
      int f = f0 + nt*16 + q16;
      float o0 = acc2[0][nt][rr] + bo[e0*SD+f];
      float o1 = acc2[1][nt][rr] + bo[e1*SD+f];
      float cmb = g0*expf(o0) + g1*expf(o1);
      if (cmb == 0.f) cmb = 2.2204460492503131e-16f;
      out[(size_t)gb*SDSQ + (size_t)s*SD + f] = logf(cmb);
    }
  }
}

extern "C" void kernel_launch(void* const* d_in, const int* in_sizes, int n_in,
                              void* d_out, int out_size, void* d_ws, size_t ws_size,
                              hipStream_t stream)
{
  const float* q  = (const float*)d_in[0];
  const float* k  = (const float*)d_in[1];
  const float* v  = (const float*)d_in[2];
  const float* wg = (const float*)d_in[4];
  const float* wn = (const float*)d_in[5];
  const float* Wq = (const float*)d_in[6];
  const float* bq = (const float*)d_in[7];
  const float* Wk = (const float*)d_in[8];
  const float* bk = (const float*)d_in[9];
  const float* Wv = (const float*)d_in[10];
  const float* bv = (const float*)d_in[11];
  const float* Wo = (const float*)d_in[12];
  const float* bo = (const float*)d_in[13];
  float* out = (float*)d_out;

  char* ws = (char*)d_ws;
  double* xs      = (double*)(ws + 0);
  int*   tk_idx   = (int*)  (ws + 131072);
  float* tk_gates = (float*)(ws + 131072 + 256);

  const size_t header = (size_t)1 << 20;
  const size_t XSB = (size_t)32 * SDSQ * 2;   // 16 MiB: one hi or lo slab of q/k/v
  const size_t WSB = (size_t)8  * SDSQ * 2;   // 4 MiB:  one hi or lo slab of a weight set
  u16t* qch = (u16t*)(ws + header + 0*XSB);
  u16t* qcl = (u16t*)(ws + header + 1*XSB);
  u16t* kh_ = (u16t*)(ws + header + 2*XSB);
  u16t* kl_ = (u16t*)(ws + header + 3*XSB);
  u16t* vh_ = (u16t*)(ws + header + 4*XSB);
  u16t* vl_ = (u16t*)(ws + header + 5*XSB);
  char* wbase = ws + header + 6*XSB;
  u16t* wqh = (u16t*)(wbase + 0*WSB);
  u16t* wql = (u16t*)(wbase + 1*WSB);
  u16t* wkh = (u16t*)(wbase + 2*WSB);
  u16t* wkl = (u16t*)(wbase + 3*WSB);
  u16t* wvh = (u16t*)(wbase + 4*WSB);
  u16t* wvl = (u16t*)(wbase + 5*WSB);
  u16t* woh = (u16t*)(wbase + 6*WSB);
  u16t* wol = (u16t*)(wbase + 7*WSB);
  char* bufbase = wbase + 8*WSB;

  const size_t perBuf = (size_t)SDSQ * 4;     // 1 MiB per pair per buffer
  size_t used = (size_t)(bufbase - ws);
  size_t avail = (ws_size > used) ? (ws_size - used) : 0;
  int CH = (int)(avail / (3 * perBuf));
  CH &= ~1;
  if (CH > 64) CH = 64;
  if (CH < 2)  CH = 2;

  // pre-pass: split inputs, split+transpose weights
  k_cvt_x<<<dim3(8192), dim3(256), 0, stream>>>(q, qch, qcl, 1);
  k_cvt_x<<<dim3(8192), dim3(256), 0, stream>>>(k, kh_, kl_, 0);
  k_cvt_x<<<dim3(8192), dim3(256), 0, stream>>>(v, vh_, vl_, 0);
  k_cvt_w<<<dim3(8,8,8), dim3(256), 0, stream>>>(Wq, wqh, wql);
  k_cvt_w<<<dim3(8,8,8), dim3(256), 0, stream>>>(Wk, wkh, wkl);
  k_cvt_w<<<dim3(8,8,8), dim3(256), 0, stream>>>(Wv, wvh, wvl);
  k_cvt_w<<<dim3(8,8,8), dim3(256), 0, stream>>>(Wo, woh, wol);

  k_xs  <<<dim3(32), dim3(512), 0, stream>>>(q, xs);
  k_gate<<<dim3(1), dim3(256), 0, stream>>>(xs, wg, wn, tk_idx, tk_gates,
                                            out + (size_t)out_size - 1);

  for (int pair0 = 0; pair0 < 64; pair0 += CH){
    int cur = (64 - pair0 < CH) ? (64 - pair0) : CH;
    float* Qb = (float*)bufbase;               // also serves as Cb (in-place)
    float* Kb = Qb + (size_t)CH * SDSQ;
    float* Vb = Kb + (size_t)CH * SDSQ;
    float* Cb = Qb;

    k_proj<<<dim3(4,4,cur*3), dim3(256), 0, stream>>>(
        qch,qcl, kh_,kl_, vh_,vl_, wqh,wql, wkh,wkl, wvh,wvl,
        bq,bk,bv, tk_idx, pair0, Qb,Kb,Vb);
    k_attn<<<dim3(8,8,cur), dim3(256), 0, stream>>>(Qb,Kb,Vb, Cb);
    k_out <<<dim3(8,8,cur/2), dim3(256), 0, stream>>>(Cb, woh, wol, bo, tk_idx, tk_gates,
                                                      pair0, out);
  }
}

// Round 3
// 801.674 us; speedup vs baseline: 1.2005x; 1.1116x over previous
//
#include <hip/hip_runtime.h>
#include <math.h>

typedef unsigned int u32;
typedef unsigned long long u64;
typedef unsigned short u16t;

#define SD   512
#define EE   8
#define DH   64
#define SDSQ (512*512)
#define LDSW 72   // padded LDS row stride (used by k_cvt_w staging and k_attn PS)

typedef __attribute__((ext_vector_type(8))) short bfrag8;
typedef __attribute__((ext_vector_type(4))) float f32x4;
typedef __attribute__((ext_vector_type(8))) unsigned short u16x8;

typedef const __attribute__((address_space(1))) void gas_void;
typedef __attribute__((address_space(3))) void las_void;

#define MFMA_B16(a,b,c) __builtin_amdgcn_mfma_f32_16x16x32_bf16((a),(b),(c),0,0,0)

__device__ __forceinline__ u32 rotl32(u32 x, int r){ return (x<<r)|(x>>(32-r)); }

__device__ __forceinline__ u16t bf_hi(float a){
  u32 x; __builtin_memcpy(&x,&a,4);
  u32 r = x + 0x7fffu + ((x>>16)&1u);
  return (u16t)(r>>16);
}
__device__ __forceinline__ float bf_f(u16t h){
  u32 x = ((u32)h)<<16; float f; __builtin_memcpy(&f,&x,4); return f;
}
__device__ __forceinline__ void split2(float a, u16t& h, u16t& l){
  h = bf_hi(a);
  l = bf_hi(a - bf_f(h));
}

// async global->LDS, 16B per lane; LDS dest is wave-uniform base + lane*16
__device__ __forceinline__ void gload16(const u16t* g, u16t* l){
  __builtin_amdgcn_global_load_lds((gas_void*)g, (las_void*)l, 16, 0, 0);
}

// threefry2x32, key = (0, 42)
__device__ __forceinline__ void threefry_0_42(u32 x0, u32 x1, u32& o0, u32& o1){
  const u32 k0=0u, k1=42u;
  const u32 ks2 = k0 ^ k1 ^ 0x1BD11BDAu;
  const int R0[4]={13,15,26,6}, R1[4]={17,29,16,24};
  x0 += k0; x1 += k1;
  #pragma unroll
  for(int r=0;r<4;r++){ x0+=x1; x1=rotl32(x1,R0[r]); x1^=x0; }
  x0+=k1; x1+=ks2+1u;
  #pragma unroll
  for(int r=0;r<4;r++){ x0+=x1; x1=rotl32(x1,R1[r]); x1^=x0; }
  x0+=ks2; x1+=k0+2u;
  #pragma unroll
  for(int r=0;r<4;r++){ x0+=x1; x1=rotl32(x1,R0[r]); x1^=x0; }
  x0+=k0; x1+=k1+3u;
  #pragma unroll
  for(int r=0;r<4;r++){ x0+=x1; x1=rotl32(x1,R1[r]); x1^=x0; }
  x0+=k1; x1+=ks2+4u;
  #pragma unroll
  for(int r=0;r<4;r++){ x0+=x1; x1=rotl32(x1,R0[r]); x1^=x0; }
  x0+=ks2; x1+=k0+5u;
  o0 = x0; o1 = x1;
}

__device__ double erfinv64(double x){
  double w = -log((1.0 - x) * (1.0 + x));
  double p;
  if (w < 5.0){
    w = w - 2.5;
    p = 2.81022636e-08;
    p = 3.43273939e-07 + p*w;
    p = -3.5233877e-06 + p*w;
    p = -4.39150654e-06 + p*w;
    p = 0.00021858087  + p*w;
    p = -0.00125372503 + p*w;
    p = -0.00417768164 + p*w;
    p = 0.246640727    + p*w;
    p = 1.50140941     + p*w;
  } else {
    w = sqrt(w) - 3.0;
    p = -0.000200214257;
    p = 0.000100950558 + p*w;
    p = 0.00134934322  + p*w;
    p = -0.00367342844 + p*w;
    p = 0.00573950773  + p*w;
    p = -0.0076224613  + p*w;
    p = 0.00943887047  + p*w;
    p = 1.00167406     + p*w;
    p = 2.83297682     + p*w;
  }
  double r = p * x;
  #pragma unroll
  for (int it=0; it<2; ++it){
    double e = erf(r) - x;
    r -= e / (1.1283791670955126 * exp(-r*r));
  }
  return r;
}

__device__ double jax_noise_part32(int i){
  u32 o0, o1;
  threefry_0_42(0u, (u32)i, o0, o1);
  u32 bits = o0 ^ o1;
  u32 fb = (bits >> 9) | 0x3f800000u;
  float f; __builtin_memcpy(&f, &fb, 4);
  f -= 1.0f;
  u32 lob = 0xBF7FFFFFu;
  float lo; __builtin_memcpy(&lo, &lob, 4);
  float t = f * 2.0f;
  float u = t + lo;
  u = fmaxf(u, lo);
  return 1.4142135623730951 * erfinv64((double)u);
}

// ---------- P0a: fp32 -> bf16 hi/lo (optionally NaN-clean), layout-preserving ----------
__global__ __launch_bounds__(256) void k_cvt_x(
  const float* __restrict__ src, u16t* __restrict__ dh, u16t* __restrict__ dl, int clean)
{
  const int n4 = 32*SDSQ/4;
  int i = blockIdx.x*256 + threadIdx.x;
  if (i >= n4) return;
  float4 r = ((const float4*)src)[i];
  float a[4] = {r.x, r.y, r.z, r.w};
  if (clean){
    #pragma unroll
    for (int u=0;u<4;u++) if (isnan(a[u])) a[u] = 0.f;
  }
  u16t h[4], l[4];
  #pragma unroll
  for (int u=0;u<4;u++) split2(a[u], h[u], l[u]);
  ((ushort4*)dh)[i] = make_ushort4(h[0],h[1],h[2],h[3]);
  ((ushort4*)dl)[i] = make_ushort4(l[0],l[1],l[2],l[3]);
}

// ---------- P0b: W[e][k][f] fp32 -> Wt[e][f][k] bf16 hi/lo (transpose + split) ----------
__global__ __launch_bounds__(256) void k_cvt_w(
  const float* __restrict__ W, u16t* __restrict__ th, u16t* __restrict__ tl)
{
  __shared__ u16t Th[64*LDSW], Tl[64*LDSW];
  int e = blockIdx.z;
  int k0 = blockIdx.y*64, f0 = blockIdx.x*64;
  int tid = threadIdx.x;
  int r = tid>>2, c4 = (tid&3)*16;
  const float* Wp = W + (size_t)e*SDSQ + (size_t)(k0+r)*SD + f0 + c4;
  #pragma unroll
  for (int i=0;i<4;i++){
    float4 rv = *(const float4*)(Wp + 4*i);
    float a[4]={rv.x,rv.y,rv.z,rv.w};
    #pragma unroll
    for (int u=0;u<4;u++){
      u16t h,l; split2(a[u],h,l);
      Th[(c4+4*i+u)*LDSW + r] = h;
      Tl[(c4+4*i+u)*LDSW + r] = l;
    }
  }
  __syncthreads();
  u16t* dh = th + (size_t)e*SDSQ + (size_t)(f0+r)*SD + k0 + c4;
  u16t* dl = tl + (size_t)e*SDSQ + (size_t)(f0+r)*SD + k0 + c4;
  *(u16x8*)dh     = *(const u16x8*)&Th[r*LDSW + c4];
  *(u16x8*)(dh+8) = *(const u16x8*)&Th[r*LDSW + c4 + 8];
  *(u16x8*)dl     = *(const u16x8*)&Tl[r*LDSW + c4];
  *(u16x8*)(dl+8) = *(const u16x8*)&Tl[r*LDSW + c4 + 8];
}

// ---------- K1: xs[b][d] = sum_s nan_to_zero(q[b][s][d])  (f64 accum) ----------
__global__ void k_xs(const float* __restrict__ q, double* __restrict__ xs){
  int b = blockIdx.x, d = threadIdx.x;
  const float* p = q + (size_t)b*SDSQ + d;
  double acc = 0.0;
  for (int s=0; s<SD; ++s){
    float f = p[(size_t)s*SD];
    if (!isnan(f)) acc += (double)f;
  }
  xs[b*SD + d] = acc;
}

// ---------- K2: gating in f64 ----------
__global__ __launch_bounds__(256) void k_gate(
    const double* __restrict__ xs, const float* __restrict__ wg,
    const float* __restrict__ wn, int* __restrict__ tk_idx,
    float* __restrict__ tk_gates, float* __restrict__ out_loss)
{
  __shared__ double cl_s[256], sd_s[256], nz_s[256], pr_s[256];
  __shared__ double thrI_s[32], thrO_s[32], g0_s[32], g1_s[32];
  __shared__ int i0_s[32], i1_s[32];
  int tid = threadIdx.x;
  int b = tid >> 3, e = tid & 7;
  double c=0.0, n=0.0;
  const double* xr = xs + b*SD;
  for (int d=0; d<SD; ++d){
    double x = xr[d];
    c += x * (double)wg[d*EE + e];
    n += x * (double)wn[d*EE + e];
  }
  double sp = fmax(n, 0.0) + log1p(exp(-fabs(n)));
  double sdv = sp + 0.01;
  double nz = c + jax_noise_part32(tid) * sdv;
  cl_s[tid]=c; sd_s[tid]=sdv; nz_s[tid]=nz;
  __syncthreads();
  if (tid < 32){
    int bb = tid;
    double v0=-INFINITY,v1=-INFINITY,v2=-INFINITY; int i0=0,i1=0;
    for (int ee=0; ee<8; ++ee){
      double vv = nz_s[bb*8+ee];
      if (vv > v0){ v2=v1; v1=v0;i1=i0; v0=vv;i0=ee; }
      else if (vv > v1){ v2=v1; v1=vv;i1=ee; }
      else if (vv > v2){ v2=vv; }
    }
    double e1 = exp(v1 - v0);
    double s = 1.0 + e1;
    double g0 = 1.0/s + 1e-9, g1 = e1/s + 1e-9;
    tk_idx[bb*2+0]=i0; tk_idx[bb*2+1]=i1;
    tk_gates[bb*2+0]=(float)g0; tk_gates[bb*2+1]=(float)g1;
    i0_s[bb]=i0; i1_s[bb]=i1; g0_s[bb]=g0; g1_s[bb]=g1;
    thrI_s[bb]=v2; thrO_s[bb]=v1;
  }
  __syncthreads();
  {
    double thrI = thrI_s[b], thrO = thrO_s[b];
    bool isin = nz_s[tid] > thrI;
    double t = (cl_s[tid] - (isin ? thrI : thrO)) / sd_s[tid];
    pr_s[tid] = 0.5 * (1.0 + erf(t * 0.7071067811865476));
  }
  __syncthreads();
  if (tid == 0){
    double imp[8], ld[8];
    for (int i=0;i<8;i++){ imp[i]=0.0; ld[i]=0.0; }
    for (int bb=0; bb<32; ++bb){
      imp[i0_s[bb]] += g0_s[bb];
      imp[i1_s[bb]] += g1_s[bb];
    }
    for (int i=0;i<256;i++) ld[i&7] += pr_s[i];
    double loss = 0.0;
    for (int a=0;a<2;a++){
      double* arr = a ? ld : imp;
      double mu=0.0; for(int i=0;i<8;i++) mu += arr[i]; mu *= 0.125;
      double var=0.0; for(int i=0;i<8;i++){ double dd=arr[i]-mu; var += dd*dd; }
      var *= (1.0/7.0);
      loss += var / (mu*mu + 1e-10);
    }
    loss *= 0.01;
    out_loss[0] = (float)loss;
  }
}

// ---------- K3: MFMA bf16x3 GEMM  Y = X @ W[e] + bias[e] ----------
// 128x128 tile, BK=64, 4 waves (2x2), global_load_lds staging with XOR chunk swizzle.
// Outputs written PRE-SPLIT (hi/lo bf16). For m==2 (V) the output is written
// TRANSPOSED (Vt[d][s]) by swapping the A/B operand roles (free).
__global__ __launch_bounds__(256) void k_proj(
  const u16t* __restrict__ qh, const u16t* __restrict__ ql,
  const u16t* __restrict__ kh, const u16t* __restrict__ kl,
  const u16t* __restrict__ vh, const u16t* __restrict__ vl,
  const u16t* __restrict__ wqh, const u16t* __restrict__ wql,
  const u16t* __restrict__ wkh, const u16t* __restrict__ wkl,
  const u16t* __restrict__ wvh, const u16t* __restrict__ wvl,
  const float* __restrict__ bq, const float* __restrict__ bk, const float* __restrict__ bv,
  const int* __restrict__ tk_idx, int pair0,
  u16t* __restrict__ Qh, u16t* __restrict__ Ql,
  u16t* __restrict__ Kh, u16t* __restrict__ Kl,
  u16t* __restrict__ Vth, u16t* __restrict__ Vtl)
{
  // SM regions (elems): A_hi @0, A_lo @8192, B_hi @16384, B_lo @24576
  __shared__ __align__(16) u16t SM[4*128*64];
  int z = blockIdx.z;
  int lp = z/3, m = z - lp*3;
  int gp = pair0 + lp;
  int b = gp >> 1;
  int e = tk_idx[gp] & 7;
  const u16t *Xh, *Xl, *Wh, *Wl; const float* bias; u16t *Yh, *Yl;
  if (m==0){ Xh=qh; Xl=ql; Wh=wqh; Wl=wql; bias=bq; Yh=Qh;  Yl=Ql;  }
  else if (m==1){ Xh=kh; Xl=kl; Wh=wkh; Wl=wkl; bias=bk; Yh=Kh;  Yl=Kl;  }
  else { Xh=vh; Xl=vl; Wh=wvh; Wl=wvl; bias=bv; Yh=Vth; Yl=Vtl; }
  bool tr = (m==2);
  Xh += (size_t)b*SDSQ; Xl += (size_t)b*SDSQ;
  Wh += (size_t)e*SDSQ; Wl += (size_t)e*SDSQ;
  bias += e*SD;
  Yh += (size_t)lp*SDSQ; Yl += (size_t)lp*SDSQ;

  int tid = threadIdx.x, w = tid>>6, lane = tid&63;
  int q16 = lane&15, quad = lane>>4;
  int wm = w>>1, wnn = w&1;
  int s0 = blockIdx.y*128, f0 = blockIdx.x*128;
  int row8 = lane>>3, cc = lane&7;
  int soff = (cc ^ row8)*8;          // inverse-swizzled source chunk (rule #21)
  int sw = q16 & 7;                  // read-side swizzle key (= row&7 of frag row)
  int aH_off = tr ? 16384 : 0;       // A operand = output-row operand
  int bH_off = tr ? 0 : 16384;

  f32x4 acc[4][4];
  #pragma unroll
  for (int i=0;i<4;i++)
    #pragma unroll
    for (int j=0;j<4;j++) acc[i][j] = (f32x4){0.f,0.f,0.f,0.f};

  for (int k0=0;k0<SD;k0+=64){
    #pragma unroll
    for (int t=0;t<4;t++){
      int br = w*32 + t*8;
      int gr = br + row8;
      size_t ga  = (size_t)(s0+gr)*SD + k0 + soff;
      size_t gbo = (size_t)(f0+gr)*SD + k0 + soff;
      gload16(Xh + ga,  &SM[0     + br*64]);
      gload16(Xl + ga,  &SM[8192  + br*64]);
      gload16(Wh + gbo, &SM[16384 + br*64]);
      gload16(Wl + gbo, &SM[24576 + br*64]);
    }
    __syncthreads();
    #pragma unroll
    for (int kk=0;kk<2;kk++){
      int ch = kk*4 + quad;
      int co = (ch ^ sw)*8;          // swizzled read chunk
      bfrag8 fAH[4], fAL[4], fBH[4], fBL[4];
      #pragma unroll
      for (int i=0;i<4;i++){
        int ra = wm*64  + i*16 + q16;
        int rb = wnn*64 + i*16 + q16;
        fAH[i] = *(const bfrag8*)&SM[aH_off        + ra*64 + co];
        fAL[i] = *(const bfrag8*)&SM[aH_off + 8192 + ra*64 + co];
        fBH[i] = *(const bfrag8*)&SM[bH_off        + rb*64 + co];
        fBL[i] = *(const bfrag8*)&SM[bH_off + 8192 + rb*64 + co];
      }
      #pragma unroll
      for (int i=0;i<4;i++)
        #pragma unroll
        for (int j=0;j<4;j++){
          acc[i][j] = MFMA_B16(fAH[i], fBH[j], acc[i][j]);
          acc[i][j] = MFMA_B16(fAH[i], fBL[j], acc[i][j]);
          acc[i][j] = MFMA_B16(fAL[i], fBH[j], acc[i][j]);
        }
    }
    __syncthreads();
  }
  if (!tr){
    #pragma unroll
    for (int i=0;i<4;i++){
      #pragma unroll
      for (int j=0;j<4;j++){
        int f = f0 + wnn*64 + j*16 + q16;
        float bb = bias[f];
        #pragma unroll
        for (int rr=0;rr<4;rr++){
          int s = s0 + wm*64 + i*16 + quad*4 + rr;
          u16t hh, ll; split2(acc[i][j][rr] + bb, hh, ll);
          size_t o = (size_t)s*SD + f;
          Yh[o] = hh; Yl[o] = ll;
        }
      }
    }
  } else {
    #pragma unroll
    for (int i=0;i<4;i++){
      #pragma unroll
      for (int rr=0;rr<4;rr++){
        int fr = f0 + wm*64 + i*16 + quad*4 + rr;
        float bb = bias[fr];
        #pragma unroll
        for (int j=0;j<4;j++){
          int scol = s0 + wnn*64 + j*16 + q16;
          u16t hh, ll; split2(acc[i][j][rr] + bb, hh, ll);
          size_t o = (size_t)fr*SD + scol;
          Yh[o] = hh; Yl[o] = ll;
        }
      }
    }
  }
}

// ---------- K4: MFMA flash attention per (pair, head, q-tile 64) ----------
// All operands pre-split; staged via global_load_lds with XOR chunk swizzle.
// ctx written pre-split (hi/lo) for k_out. Ch/Cl alias Qh/Ql (own-tile in-place).
__global__ __launch_bounds__(256) void k_attn(
  const u16t* __restrict__ Qh, const u16t* __restrict__ Ql,
  const u16t* __restrict__ Kh, const u16t* __restrict__ Kl,
  const u16t* __restrict__ Vth, const u16t* __restrict__ Vtl,
  u16t* __restrict__ Ch, u16t* __restrict__ Cl)
{
  __shared__ __align__(16) u16t QH[64*64], QL[64*64];   // [q][d]
  __shared__ __align__(16) u16t KH[64*64], KL[64*64];   // [key][d]
  __shared__ __align__(16) u16t VTH[64*64], VTL[64*64]; // [dh][key]
  __shared__ __align__(16) u16t PS[64*LDSW];            // [q][key] (padded)
  int lp = blockIdx.z, h = blockIdx.y, qt = blockIdx.x;
  int tid = threadIdx.x;
  int w = tid>>6, lane = tid&63, q16 = lane&15, quad = lane>>4;
  int s0 = qt*64;
  const size_t base  = (size_t)lp*SDSQ + h*DH;             // [s][512] slabs
  const size_t vbase = (size_t)lp*SDSQ + (size_t)h*DH*SD;  // Vt [d][512]
  int row8 = lane>>3, cc = lane&7;
  int soff = (cc ^ row8)*8;
  int sw = q16 & 7;

  // stage Q once (waits folded into first kt barrier)
  #pragma unroll
  for (int t=0;t<2;t++){
    int br = w*16 + t*8, gr = br + row8;
    size_t ga = base + (size_t)(s0+gr)*SD + soff;
    gload16(Qh + ga, &QH[br*64]);
    gload16(Ql + ga, &QL[br*64]);
  }

  float m_row[4], l_row[4];
  f32x4 ctx[4];
  #pragma unroll
  for (int rr=0;rr<4;rr++){ m_row[rr]=-INFINITY; l_row[rr]=0.f; }
  #pragma unroll
  for (int nt=0;nt<4;nt++) ctx[nt] = (f32x4){0.f,0.f,0.f,0.f};

  for (int kt=0; kt<8; ++kt){
    // stage K and V^T
    #pragma unroll
    for (int t=0;t<2;t++){
      int br = w*16 + t*8, gr = br + row8;
      size_t gk = base + (size_t)(kt*64+gr)*SD + soff;
      gload16(Kh + gk, &KH[br*64]);
      gload16(Kl + gk, &KL[br*64]);
      size_t gv = vbase + (size_t)gr*SD + kt*64 + soff;
      gload16(Vth + gv, &VTH[br*64]);
      gload16(Vtl + gv, &VTL[br*64]);
    }
    __syncthreads();

    // scores = Q K^T (bf16x3)
    f32x4 sc[4];
    #pragma unroll
    for (int nt=0;nt<4;nt++) sc[nt] = (f32x4){0.f,0.f,0.f,0.f};
    #pragma unroll
    for (int kk=0;kk<2;kk++){
      int co = ((kk*4+quad) ^ sw)*8;
      bfrag8 aH = *(const bfrag8*)&QH[(w*16+q16)*64 + co];
      bfrag8 aL = *(const bfrag8*)&QL[(w*16+q16)*64 + co];
      #pragma unroll
      for (int nt=0;nt<4;nt++){
        bfrag8 bH = *(const bfrag8*)&KH[(nt*16+q16)*64 + co];
        bfrag8 bL = *(const bfrag8*)&KL[(nt*16+q16)*64 + co];
        sc[nt] = MFMA_B16(aH,bH,sc[nt]);
        sc[nt] = MFMA_B16(aH,bL,sc[nt]);
        sc[nt] = MFMA_B16(aL,bH,sc[nt]);
      }
    }
    #pragma unroll
    for (int nt=0;nt<4;nt++)
      #pragma unroll
      for (int rr=0;rr<4;rr++) sc[nt][rr] *= 0.125f;

    float alpha[4];
    #pragma unroll
    for (int rr=0;rr<4;rr++){
      float mx = sc[0][rr];
      #pragma unroll
      for (int nt=1;nt<4;nt++) mx = fmaxf(mx, sc[nt][rr]);
      mx = fmaxf(mx, __shfl_xor(mx, 1));
      mx = fmaxf(mx, __shfl_xor(mx, 2));
      mx = fmaxf(mx, __shfl_xor(mx, 4));
      mx = fmaxf(mx, __shfl_xor(mx, 8));
      float nm = fmaxf(m_row[rr], mx);
      alpha[rr] = expf(m_row[rr] - nm);
      m_row[rr] = nm;
    }
    #pragma unroll
    for (int rr=0;rr<4;rr++){
      float S = 0.f;
      #pragma unroll
      for (int nt=0;nt<4;nt++){
        float p = expf(sc[nt][rr] - m_row[rr]);
        sc[nt][rr] = p;
        S += p;
      }
      S += __shfl_xor(S, 1);
      S += __shfl_xor(S, 2);
      S += __shfl_xor(S, 4);
      S += __shfl_xor(S, 8);
      l_row[rr] = l_row[rr]*alpha[rr] + S;
      #pragma unroll
      for (int nt=0;nt<4;nt++) ctx[nt][rr] *= alpha[rr];
    }
    #pragma unroll
    for (int nt=0;nt<4;nt++)
      #pragma unroll
      for (int rr=0;rr<4;rr++)
        PS[(w*16 + quad*4 + rr)*LDSW + nt*16 + q16] = bf_hi(sc[nt][rr]);
    __syncthreads();

    // ctx += P V  (P plain bf16, V bf16x2)
    #pragma unroll
    for (int kk2=0;kk2<2;kk2++){
      bfrag8 aP = *(const bfrag8*)&PS[(w*16+q16)*LDSW + kk2*32 + quad*8];
      int co2 = ((kk2*4+quad) ^ sw)*8;
      #pragma unroll
      for (int nt=0;nt<4;nt++){
        bfrag8 vH = *(const bfrag8*)&VTH[(nt*16+q16)*64 + co2];
        bfrag8 vL = *(const bfrag8*)&VTL[(nt*16+q16)*64 + co2];
        ctx[nt] = MFMA_B16(aP,vH,ctx[nt]);
        ctx[nt] = MFMA_B16(aP,vL,ctx[nt]);
      }
    }
    __syncthreads();
  }
  // epilogue: split and store (Ch/Cl alias Qh/Ql: we overwrite only our own tile)
  #pragma unroll
  for (int rr=0;rr<4;rr++){
    float inv = 1.f / l_row[rr];
    #pragma unroll
    for (int nt=0;nt<4;nt++){
      int s = s0 + w*16 + quad*4 + rr;
      u16t hh, ll; split2(ctx[nt][rr]*inv, hh, ll);
      size_t o = base + (size_t)s*SD + nt*16 + q16;
      Ch[o] = hh; Cl[o] = ll;
    }
  }
}

// ---------- K5: MFMA bf16x3: out = log(sum_j g_j * exp(ctx_j @ Wo[e_j] + bo[e_j])) ----------
// Both operands pre-split; staged via global_load_lds with XOR chunk swizzle.
__global__ __launch_bounds__(256) void k_out(
  const u16t* __restrict__ Ch, const u16t* __restrict__ Cl,
  const u16t* __restrict__ Wth, const u16t* __restrict__ Wtl,
  const float* __restrict__ bo, const int* __restrict__ tk_idx,
  const float* __restrict__ tk_gates, int pair0, float* __restrict__ out)
{
  __shared__ __align__(16) u16t Ah[64*64], Al[64*64];
  __shared__ __align__(16) u16t Bh[64*64], Bl[64*64];   // [f][k]
  int lb = blockIdx.z;
  int gb = (pair0 >> 1) + lb;
  int tid = threadIdx.x;
  int w = tid>>6, lane = tid&63, q16 = lane&15, quad = lane>>4;
  int s0 = blockIdx.y*64, f0 = blockIdx.x*64;
  int row8 = lane>>3, cc = lane&7;
  int soff = (cc ^ row8)*8;
  int sw = q16 & 7;

  f32x4 acc2[2][4];
  #pragma unroll
  for (int j=0;j<2;j++)
    #pragma unroll
    for (int nt=0;nt<4;nt++) acc2[j][nt] = (f32x4){0.f,0.f,0.f,0.f};

  for (int j=0;j<2;++j){
    int e = tk_idx[pair0 + lb*2 + j] & 7;
    const u16t* AH = Ch + (size_t)(lb*2+j)*SDSQ;
    const u16t* AL = Cl + (size_t)(lb*2+j)*SDSQ;
    const u16t* WH = Wth + (size_t)e*SDSQ;
    const u16t* WL = Wtl + (size_t)e*SDSQ;
    for (int k0=0;k0<SD;k0+=64){
      #pragma unroll
      for (int t=0;t<2;t++){
        int br = w*16 + t*8, gr = br + row8;
        size_t ga  = (size_t)(s0+gr)*SD + k0 + soff;
        size_t gbo = (size_t)(f0+gr)*SD + k0 + soff;
        gload16(AH + ga,  &Ah[br*64]);
        gload16(AL + ga,  &Al[br*64]);
        gload16(WH + gbo, &Bh[br*64]);
        gload16(WL + gbo, &Bl[br*64]);
      }
      __syncthreads();
      #pragma unroll
      for (int kk=0;kk<2;kk++){
        int co = ((kk*4+quad) ^ sw)*8;
        bfrag8 aH = *(const bfrag8*)&Ah[(w*16+q16)*64 + co];
        bfrag8 aL = *(const bfrag8*)&Al[(w*16+q16)*64 + co];
        #pragma unroll
        for (int nt=0;nt<4;nt++){
          bfrag8 bH = *(const bfrag8*)&Bh[(nt*16+q16)*64 + co];
          bfrag8 bL = *(const bfrag8*)&Bl[(nt*16+q16)*64 + co];
          acc2[j][nt] = MFMA_B16(aH,bH,acc2[j][nt]);
          acc2[j][nt] = MFMA_B16(aH,bL,acc2[j][nt]);
          acc2[j][nt] = MFMA_B16(aL,bH,acc2[j][nt]);
        }
      }
      __syncthreads();
    }
  }
  int e0 = tk_idx[pair0 + lb*2 + 0] & 7, e1 = tk_idx[pair0 + lb*2 + 1] & 7;
  float g0 = tk_gates[pair0 + lb*2 + 0], g1 = tk_gates[pair0 + lb*2 + 1];
  #pragma unroll
  for (int nt=0;nt<4;nt++){
    #pragma unroll
    for (int rr=0;rr<4;rr++){
      int s = s0 + w*16 + quad*4 + rr;
      int f = f0 + nt*16 + q16;
      float o0 = acc2[0][nt][rr] + bo[e0*SD+f];
      float o1 = acc2[1][nt][rr] + bo[e1*SD+f];
      float cmb = g0*expf(o0) + g1*expf(o1);
      if (cmb == 0.f) cmb = 2.2204460492503131e-16f;
      out[(size_t)gb*SDSQ + (size_t)s*SD + f] = logf(cmb);
    }
  }
}

extern "C" void kernel_launch(void* const* d_in, const int* in_sizes, int n_in,
                              void* d_out, int out_size, void* d_ws, size_t ws_size,
                              hipStream_t stream)
{
  const float* q  = (const float*)d_in[0];
  const float* k  = (const float*)d_in[1];
  const float* v  = (const float*)d_in[2];
  const float* wg = (const float*)d_in[4];
  const float* wn = (const float*)d_in[5];
  const float* Wq = (const float*)d_in[6];
  const float* bq = (const float*)d_in[7];
  const float* Wk = (const float*)d_in[8];
  const float* bk = (const float*)d_in[9];
  const float* Wv = (const float*)d_in[10];
  const float* bv = (const float*)d_in[11];
  const float* Wo = (const float*)d_in[12];
  const float* bo = (const float*)d_in[13];
  float* out = (float*)d_out;

  char* ws = (char*)d_ws;
  double* xs      = (double*)(ws + 0);
  int*   tk_idx   = (int*)  (ws + 131072);
  float* tk_gates = (float*)(ws + 131072 + 256);

  const size_t header = (size_t)1 << 20;
  const size_t XSB = (size_t)32 * SDSQ * 2;   // 16 MiB: one hi or lo slab of q/k/v
  const size_t WSB = (size_t)8  * SDSQ * 2;   // 4 MiB:  one hi or lo slab of a weight set
  u16t* qch = (u16t*)(ws + header + 0*XSB);
  u16t* qcl = (u16t*)(ws + header + 1*XSB);
  u16t* kh_ = (u16t*)(ws + header + 2*XSB);
  u16t* kl_ = (u16t*)(ws + header + 3*XSB);
  u16t* vh_ = (u16t*)(ws + header + 4*XSB);
  u16t* vl_ = (u16t*)(ws + header + 5*XSB);
  char* wbase = ws + header + 6*XSB;
  u16t* wqh = (u16t*)(wbase + 0*WSB);
  u16t* wql = (u16t*)(wbase + 1*WSB);
  u16t* wkh = (u16t*)(wbase + 2*WSB);
  u16t* wkl = (u16t*)(wbase + 3*WSB);
  u16t* wvh = (u16t*)(wbase + 4*WSB);
  u16t* wvl = (u16t*)(wbase + 5*WSB);
  u16t* woh = (u16t*)(wbase + 6*WSB);
  u16t* wol = (u16t*)(wbase + 7*WSB);
  char* bufbase = wbase + 8*WSB;

  const size_t slab = (size_t)SDSQ * 2;       // 0.5 MiB per pair per slab; 6 slabs/pair
  size_t used = (size_t)(bufbase - ws);
  size_t avail = (ws_size > used) ? (ws_size - used) : 0;
  int CH = (int)(avail / (6 * slab));
  CH &= ~1;
  if (CH > 64) CH = 64;
  if (CH < 2)  CH = 2;

  // pre-pass: split inputs, split+transpose weights
  k_cvt_x<<<dim3(8192), dim3(256), 0, stream>>>(q, qch, qcl, 1);
  k_cvt_x<<<dim3(8192), dim3(256), 0, stream>>>(k, kh_, kl_, 0);
  k_cvt_x<<<dim3(8192), dim3(256), 0, stream>>>(v, vh_, vl_, 0);
  k_cvt_w<<<dim3(8,8,8), dim3(256), 0, stream>>>(Wq, wqh, wql);
  k_cvt_w<<<dim3(8,8,8), dim3(256), 0, stream>>>(Wk, wkh, wkl);
  k_cvt_w<<<dim3(8,8,8), dim3(256), 0, stream>>>(Wv, wvh, wvl);
  k_cvt_w<<<dim3(8,8,8), dim3(256), 0, stream>>>(Wo, woh, wol);

  k_xs  <<<dim3(32), dim3(512), 0, stream>>>(q, xs);
  k_gate<<<dim3(1), dim3(256), 0, stream>>>(xs, wg, wn, tk_idx, tk_gates,
                                            out + (size_t)out_size - 1);

  for (int pair0 = 0; pair0 < 64; pair0 += CH){
    int cur = (64 - pair0 < CH) ? (64 - pair0) : CH;
    u16t* Qh  = (u16t*)bufbase;
    u16t* Ql  = Qh  + (size_t)CH * SDSQ;
    u16t* Kh  = Ql  + (size_t)CH * SDSQ;
    u16t* Kl  = Kh  + (size_t)CH * SDSQ;
    u16t* Vth = Kl  + (size_t)CH * SDSQ;
    u16t* Vtl = Vth + (size_t)CH * SDSQ;
    u16t* Ch = Qh;   // ctx in-place over Q slabs
    u16t* Cl = Ql;

    k_proj<<<dim3(4,4,cur*3), dim3(256), 0, stream>>>(
        qch,qcl, kh_,kl_, vh_,vl_, wqh,wql, wkh,wkl, wvh,wvl,
        bq,bk,bv, tk_idx, pair0, Qh,Ql, Kh,Kl, Vth,Vtl);
    k_attn<<<dim3(8,8,cur), dim3(256), 0, stream>>>(Qh,Ql, Kh,Kl, Vth,Vtl, Ch,Cl);
    k_out <<<dim3(8,8,cur/2), dim3(256), 0, stream>>>(Ch,Cl, woh,wol, bo, tk_idx, tk_gates,
                                                      pair0, out);
  }
}

// Round 6
// 761.742 us; speedup vs baseline: 1.2635x; 1.0524x over previous
//
#include <hip/hip_runtime.h>
#include <math.h>

typedef unsigned int u32;
typedef unsigned long long u64;
typedef unsigned short u16t;

#define SD   512
#define EE   8
#define DH   64
#define SDSQ (512*512)
#define LDSW 72   // padded LDS row stride (used by k_cvt_w staging)

typedef __attribute__((ext_vector_type(8))) short bfrag8;
typedef __attribute__((ext_vector_type(4))) float f32x4;
typedef __attribute__((ext_vector_type(8))) unsigned short u16x8;

typedef const __attribute__((address_space(1))) void gas_void;
typedef __attribute__((address_space(3))) void las_void;

#define MFMA_B16(a,b,c) __builtin_amdgcn_mfma_f32_16x16x32_bf16((a),(b),(c),0,0,0)

__device__ __forceinline__ u32 rotl32(u32 x, int r){ return (x<<r)|(x>>(32-r)); }

__device__ __forceinline__ u16t bf_hi(float a){
  u32 x; __builtin_memcpy(&x,&a,4);
  u32 r = x + 0x7fffu + ((x>>16)&1u);
  return (u16t)(r>>16);
}
__device__ __forceinline__ float bf_f(u16t h){
  u32 x = ((u32)h)<<16; float f; __builtin_memcpy(&f,&x,4); return f;
}
__device__ __forceinline__ void split2(float a, u16t& h, u16t& l){
  h = bf_hi(a);
  l = bf_hi(a - bf_f(h));
}

// async global->LDS, 16B per lane; LDS dest is wave-uniform base + lane*16
__device__ __forceinline__ void gload16(const u16t* g, u16t* l){
  __builtin_amdgcn_global_load_lds((gas_void*)g, (las_void*)l, 16, 0, 0);
}

// threefry2x32, key = (0, 42)
__device__ __forceinline__ void threefry_0_42(u32 x0, u32 x1, u32& o0, u32& o1){
  const u32 k0=0u, k1=42u;
  const u32 ks2 = k0 ^ k1 ^ 0x1BD11BDAu;
  const int R0[4]={13,15,26,6}, R1[4]={17,29,16,24};
  x0 += k0; x1 += k1;
  #pragma unroll
  for(int r=0;r<4;r++){ x0+=x1; x1=rotl32(x1,R0[r]); x1^=x0; }
  x0+=k1; x1+=ks2+1u;
  #pragma unroll
  for(int r=0;r<4;r++){ x0+=x1; x1=rotl32(x1,R1[r]); x1^=x0; }
  x0+=ks2; x1+=k0+2u;
  #pragma unroll
  for(int r=0;r<4;r++){ x0+=x1; x1=rotl32(x1,R0[r]); x1^=x0; }
  x0+=k0; x1+=k1+3u;
  #pragma unroll
  for(int r=0;r<4;r++){ x0+=x1; x1=rotl32(x1,R1[r]); x1^=x0; }
  x0+=k1; x1+=ks2+4u;
  #pragma unroll
  for(int r=0;r<4;r++){ x0+=x1; x1=rotl32(x1,R0[r]); x1^=x0; }
  x0+=ks2; x1+=k0+5u;
  o0 = x0; o1 = x1;
}

__device__ double erfinv64(double x){
  double w = -log((1.0 - x) * (1.0 + x));
  double p;
  if (w < 5.0){
    w = w - 2.5;
    p = 2.81022636e-08;
    p = 3.43273939e-07 + p*w;
    p = -3.5233877e-06 + p*w;
    p = -4.39150654e-06 + p*w;
    p = 0.00021858087  + p*w;
    p = -0.00125372503 + p*w;
    p = -0.00417768164 + p*w;
    p = 0.246640727    + p*w;
    p = 1.50140941     + p*w;
  } else {
    w = sqrt(w) - 3.0;
    p = -0.000200214257;
    p = 0.000100950558 + p*w;
    p = 0.00134934322  + p*w;
    p = -0.00367342844 + p*w;
    p = 0.00573950773  + p*w;
    p = -0.0076224613  + p*w;
    p = 0.00943887047  + p*w;
    p = 1.00167406     + p*w;
    p = 2.83297682     + p*w;
  }
  double r = p * x;
  #pragma unroll
  for (int it=0; it<2; ++it){
    double e = erf(r) - x;
    r -= e / (1.1283791670955126 * exp(-r*r));
  }
  return r;
}

__device__ double jax_noise_part32(int i){
  u32 o0, o1;
  threefry_0_42(0u, (u32)i, o0, o1);
  u32 bits = o0 ^ o1;
  u32 fb = (bits >> 9) | 0x3f800000u;
  float f; __builtin_memcpy(&f, &fb, 4);
  f -= 1.0f;
  u32 lob = 0xBF7FFFFFu;
  float lo; __builtin_memcpy(&lo, &lob, 4);
  float t = f * 2.0f;
  float u = t + lo;
  u = fmaxf(u, lo);
  return 1.4142135623730951 * erfinv64((double)u);
}

// ---------- P0a: fp32 -> bf16 hi/lo (optionally NaN-clean), layout-preserving ----------
__global__ __launch_bounds__(256) void k_cvt_x(
  const float* __restrict__ src, u16t* __restrict__ dh, u16t* __restrict__ dl, int clean)
{
  const int n4 = 32*SDSQ/4;
  int i = blockIdx.x*256 + threadIdx.x;
  if (i >= n4) return;
  float4 r = ((const float4*)src)[i];
  float a[4] = {r.x, r.y, r.z, r.w};
  if (clean){
    #pragma unroll
    for (int u=0;u<4;u++) if (isnan(a[u])) a[u] = 0.f;
  }
  u16t h[4], l[4];
  #pragma unroll
  for (int u=0;u<4;u++) split2(a[u], h[u], l[u]);
  ((ushort4*)dh)[i] = make_ushort4(h[0],h[1],h[2],h[3]);
  ((ushort4*)dl)[i] = make_ushort4(l[0],l[1],l[2],l[3]);
}

// ---------- P0b: W[e][k][f] fp32 -> Wt[e][f][k] bf16 hi/lo (transpose + split) ----------
__global__ __launch_bounds__(256) void k_cvt_w(
  const float* __restrict__ W, u16t* __restrict__ th, u16t* __restrict__ tl)
{
  __shared__ u16t Th[64*LDSW], Tl[64*LDSW];
  int e = blockIdx.z;
  int k0 = blockIdx.y*64, f0 = blockIdx.x*64;
  int tid = threadIdx.x;
  int r = tid>>2, c4 = (tid&3)*16;
  const float* Wp = W + (size_t)e*SDSQ + (size_t)(k0+r)*SD + f0 + c4;
  #pragma unroll
  for (int i=0;i<4;i++){
    float4 rv = *(const float4*)(Wp + 4*i);
    float a[4]={rv.x,rv.y,rv.z,rv.w};
    #pragma unroll
    for (int u=0;u<4;u++){
      u16t h,l; split2(a[u],h,l);
      Th[(c4+4*i+u)*LDSW + r] = h;
      Tl[(c4+4*i+u)*LDSW + r] = l;
    }
  }
  __syncthreads();
  u16t* dh = th + (size_t)e*SDSQ + (size_t)(f0+r)*SD + k0 + c4;
  u16t* dl = tl + (size_t)e*SDSQ + (size_t)(f0+r)*SD + k0 + c4;
  *(u16x8*)dh     = *(const u16x8*)&Th[r*LDSW + c4];
  *(u16x8*)(dh+8) = *(const u16x8*)&Th[r*LDSW + c4 + 8];
  *(u16x8*)dl     = *(const u16x8*)&Tl[r*LDSW + c4];
  *(u16x8*)(dl+8) = *(const u16x8*)&Tl[r*LDSW + c4 + 8];
}

// ---------- K1: xs[b][d] = sum_s nan_to_zero(q[b][s][d])  (f64 accum) ----------
__global__ void k_xs(const float* __restrict__ q, double* __restrict__ xs){
  int b = blockIdx.x, d = threadIdx.x;
  const float* p = q + (size_t)b*SDSQ + d;
  double acc = 0.0;
  for (int s=0; s<SD; ++s){
    float f = p[(size_t)s*SD];
    if (!isnan(f)) acc += (double)f;
  }
  xs[b*SD + d] = acc;
}

// ---------- K2: gating in f64 ----------
__global__ __launch_bounds__(256) void k_gate(
    const double* __restrict__ xs, const float* __restrict__ wg,
    const float* __restrict__ wn, int* __restrict__ tk_idx,
    float* __restrict__ tk_gates, float* __restrict__ out_loss)
{
  __shared__ double cl_s[256], sd_s[256], nz_s[256], pr_s[256];
  __shared__ double thrI_s[32], thrO_s[32], g0_s[32], g1_s[32];
  __shared__ int i0_s[32], i1_s[32];
  int tid = threadIdx.x;
  int b = tid >> 3, e = tid & 7;
  double c=0.0, n=0.0;
  const double* xr = xs + b*SD;
  for (int d=0; d<SD; ++d){
    double x = xr[d];
    c += x * (double)wg[d*EE + e];
    n += x * (double)wn[d*EE + e];
  }
  double sp = fmax(n, 0.0) + log1p(exp(-fabs(n)));
  double sdv = sp + 0.01;
  double nz = c + jax_noise_part32(tid) * sdv;
  cl_s[tid]=c; sd_s[tid]=sdv; nz_s[tid]=nz;
  __syncthreads();
  if (tid < 32){
    int bb = tid;
    double v0=-INFINITY,v1=-INFINITY,v2=-INFINITY; int i0=0,i1=0;
    for (int ee=0; ee<8; ++ee){
      double vv = nz_s[bb*8+ee];
      if (vv > v0){ v2=v1; v1=v0;i1=i0; v0=vv;i0=ee; }
      else if (vv > v1){ v2=v1; v1=vv;i1=ee; }
      else if (vv > v2){ v2=vv; }
    }
    double e1 = exp(v1 - v0);
    double s = 1.0 + e1;
    double g0 = 1.0/s + 1e-9, g1 = e1/s + 1e-9;
    tk_idx[bb*2+0]=i0; tk_idx[bb*2+1]=i1;
    tk_gates[bb*2+0]=(float)g0; tk_gates[bb*2+1]=(float)g1;
    i0_s[bb]=i0; i1_s[bb]=i1; g0_s[bb]=g0; g1_s[bb]=g1;
    thrI_s[bb]=v2; thrO_s[bb]=v1;
  }
  __syncthreads();
  {
    double thrI = thrI_s[b], thrO = thrO_s[b];
    bool isin = nz_s[tid] > thrI;
    double t = (cl_s[tid] - (isin ? thrI : thrO)) / sd_s[tid];
    pr_s[tid] = 0.5 * (1.0 + erf(t * 0.7071067811865476));
  }
  __syncthreads();
  if (tid == 0){
    double imp[8], ld[8];
    for (int i=0;i<8;i++){ imp[i]=0.0; ld[i]=0.0; }
    for (int bb=0; bb<32; ++bb){
      imp[i0_s[bb]] += g0_s[bb];
      imp[i1_s[bb]] += g1_s[bb];
    }
    for (int i=0;i<256;i++) ld[i&7] += pr_s[i];
    double loss = 0.0;
    for (int a=0;a<2;a++){
      double* arr = a ? ld : imp;
      double mu=0.0; for(int i=0;i<8;i++) mu += arr[i]; mu *= 0.125;
      double var=0.0; for(int i=0;i<8;i++){ double dd=arr[i]-mu; var += dd*dd; }
      var *= (1.0/7.0);
      loss += var / (mu*mu + 1e-10);
    }
    loss *= 0.01;
    out_loss[0] = (float)loss;
  }
}

// ---------- K3: MFMA bf16x3 GEMM  Y = X @ W[e] + bias[e] ----------
// 128x128 tile, BK=64, 4 waves (2x2), global_load_lds staging with XOR chunk swizzle.
// Outputs written PRE-SPLIT (hi/lo bf16). For m==2 (V) the output is written
// TRANSPOSED (Vt[d][s]) by swapping the A/B operand roles (free).
// Grid remapped so each z-group's 16 blocks land in one XCD chunk.
__global__ __launch_bounds__(256) void k_proj(
  const u16t* __restrict__ qh, const u16t* __restrict__ ql,
  const u16t* __restrict__ kh, const u16t* __restrict__ kl,
  const u16t* __restrict__ vh, const u16t* __restrict__ vl,
  const u16t* __restrict__ wqh, const u16t* __restrict__ wql,
  const u16t* __restrict__ wkh, const u16t* __restrict__ wkl,
  const u16t* __restrict__ wvh, const u16t* __restrict__ wvl,
  const float* __restrict__ bq, const float* __restrict__ bk, const float* __restrict__ bv,
  const int* __restrict__ tk_idx, int pair0,
  u16t* __restrict__ Qh, u16t* __restrict__ Ql,
  u16t* __restrict__ Kh, u16t* __restrict__ Kl,
  u16t* __restrict__ Vth, u16t* __restrict__ Vtl)
{
  // SM regions (elems): A_hi @0, A_lo @8192, B_hi @16384, B_lo @24576
  __shared__ __align__(16) u16t SM[4*128*64];
  int Nb = gridDim.x*gridDim.y*gridDim.z;
  int flat = blockIdx.x + gridDim.x*(blockIdx.y + gridDim.y*blockIdx.z);
  int nf = (flat & 7)*(Nb>>3) + (flat>>3);
  int bxx = nf & 3, byy = (nf>>2) & 3, z = nf >> 4;
  int lp = z/3, m = z - lp*3;
  int gp = pair0 + lp;
  int b = gp >> 1;
  int e = tk_idx[gp] & 7;
  const u16t *Xh, *Xl, *Wh, *Wl; const float* bias; u16t *Yh, *Yl;
  if (m==0){ Xh=qh; Xl=ql; Wh=wqh; Wl=wql; bias=bq; Yh=Qh;  Yl=Ql;  }
  else if (m==1){ Xh=kh; Xl=kl; Wh=wkh; Wl=wkl; bias=bk; Yh=Kh;  Yl=Kl;  }
  else { Xh=vh; Xl=vl; Wh=wvh; Wl=wvl; bias=bv; Yh=Vth; Yl=Vtl; }
  bool tr = (m==2);
  Xh += (size_t)b*SDSQ; Xl += (size_t)b*SDSQ;
  Wh += (size_t)e*SDSQ; Wl += (size_t)e*SDSQ;
  bias += e*SD;
  Yh += (size_t)lp*SDSQ; Yl += (size_t)lp*SDSQ;

  int tid = threadIdx.x, w = tid>>6, lane = tid&63;
  int q16 = lane&15, quad = lane>>4;
  int wm = w>>1, wnn = w&1;
  int s0 = byy*128, f0 = bxx*128;
  int row8 = lane>>3, cc = lane&7;
  int soff = (cc ^ row8)*8;          // inverse-swizzled source chunk (rule #21)
  int sw = q16 & 7;                  // read-side swizzle key (= row&7 of frag row)
  int aH_off = tr ? 16384 : 0;       // A operand = output-row operand
  int bH_off = tr ? 0 : 16384;

  f32x4 acc[4][4];
  #pragma unroll
  for (int i=0;i<4;i++)
    #pragma unroll
    for (int j=0;j<4;j++) acc[i][j] = (f32x4){0.f,0.f,0.f,0.f};

  for (int k0=0;k0<SD;k0+=64){
    #pragma unroll
    for (int t=0;t<4;t++){
      int br = w*32 + t*8;
      int gr = br + row8;
      size_t ga  = (size_t)(s0+gr)*SD + k0 + soff;
      size_t gbo = (size_t)(f0+gr)*SD + k0 + soff;
      gload16(Xh + ga,  &SM[0     + br*64]);
      gload16(Xl + ga,  &SM[8192  + br*64]);
      gload16(Wh + gbo, &SM[16384 + br*64]);
      gload16(Wl + gbo, &SM[24576 + br*64]);
    }
    __syncthreads();
    #pragma unroll
    for (int kk=0;kk<2;kk++){
      int ch = kk*4 + quad;
      int co = (ch ^ sw)*8;          // swizzled read chunk
      bfrag8 fAH[4], fAL[4], fBH[4], fBL[4];
      #pragma unroll
      for (int i=0;i<4;i++){
        int ra = wm*64  + i*16 + q16;
        int rb = wnn*64 + i*16 + q16;
        fAH[i] = *(const bfrag8*)&SM[aH_off        + ra*64 + co];
        fAL[i] = *(const bfrag8*)&SM[aH_off + 8192 + ra*64 + co];
        fBH[i] = *(const bfrag8*)&SM[bH_off        + rb*64 + co];
        fBL[i] = *(const bfrag8*)&SM[bH_off + 8192 + rb*64 + co];
      }
      #pragma unroll
      for (int i=0;i<4;i++)
        #pragma unroll
        for (int j=0;j<4;j++){
          acc[i][j] = MFMA_B16(fAH[i], fBH[j], acc[i][j]);
          acc[i][j] = MFMA_B16(fAH[i], fBL[j], acc[i][j]);
          acc[i][j] = MFMA_B16(fAL[i], fBH[j], acc[i][j]);
        }
    }
    __syncthreads();
  }
  if (!tr){
    #pragma unroll
    for (int i=0;i<4;i++){
      #pragma unroll
      for (int j=0;j<4;j++){
        int f = f0 + wnn*64 + j*16 + q16;
        float bb = bias[f];
        #pragma unroll
        for (int rr=0;rr<4;rr++){
          int s = s0 + wm*64 + i*16 + quad*4 + rr;
          u16t hh, ll; split2(acc[i][j][rr] + bb, hh, ll);
          size_t o = (size_t)s*SD + f;
          Yh[o] = hh; Yl[o] = ll;
        }
      }
    }
  } else {
    #pragma unroll
    for (int i=0;i<4;i++){
      #pragma unroll
      for (int rr=0;rr<4;rr++){
        int fr = f0 + wm*64 + i*16 + quad*4 + rr;
        float bb = bias[fr];
        #pragma unroll
        for (int j=0;j<4;j++){
          int scol = s0 + wnn*64 + j*16 + q16;
          u16t hh, ll; split2(acc[i][j][rr] + bb, hh, ll);
          size_t o = (size_t)fr*SD + scol;
          Yh[o] = hh; Yl[o] = ll;
        }
      }
    }
  }
}

// ---------- K4: MFMA flash attention per (pair, head, q-tile 64) ----------
// Q fragments held in registers (loaded directly from pre-split global slabs).
// K/V^T single-buffered in LDS via global_load_lds + XOR chunk swizzle
// (2 issues/wave/slab: each wave64 x 16B covers 8 rows; 64-row slab needs 8 issues).
// PS [64][64] chunk-XOR-swizzled (wave-private rows: no barrier needed).
// LDS = 40 KB -> 4 blocks/CU. Bijective XCD swizzle keeps the 8 q-tiles of one
// (pair,head) in one XCD chunk for K/V L2 reuse.
__global__ __launch_bounds__(256, 4) void k_attn(
  const u16t* __restrict__ Qh, const u16t* __restrict__ Ql,
  const u16t* __restrict__ Kh, const u16t* __restrict__ Kl,
  const u16t* __restrict__ Vth, const u16t* __restrict__ Vtl,
  u16t* __restrict__ Ch, u16t* __restrict__ Cl)
{
  // elems: KH@0, KL@4096, VTH@8192, VTL@12288, PS@16384 ([64][64] swz)
  __shared__ __align__(16) u16t SM[20480];
  int tid = threadIdx.x;
  int w = tid>>6, lane = tid&63, q16 = lane&15, quad = lane>>4;
  int Nb = gridDim.x*gridDim.y*gridDim.z;
  int flat = blockIdx.x + gridDim.x*(blockIdx.y + gridDim.y*blockIdx.z);
  int nf = (flat & 7)*(Nb>>3) + (flat>>3);
  int qt = nf & 7, h = (nf>>3) & 7, lp = nf >> 6;
  int s0 = qt*64;
  const size_t base  = (size_t)lp*SDSQ + h*DH;             // [s][512] slabs
  const size_t vbase = (size_t)lp*SDSQ + (size_t)h*DH*SD;  // Vt [d][512]
  int row8 = lane>>3, cc = lane&7;
  int soff = (cc ^ row8)*8;
  int sw = q16 & 7;

  // Q fragments -> registers (rows s0 + w*16 + q16, cols kk*32 + quad*8)
  bfrag8 qH[2], qL[2];
  {
    const u16t* qp  = Qh + base + (size_t)(s0 + w*16 + q16)*SD + quad*8;
    const u16t* qp2 = Ql + base + (size_t)(s0 + w*16 + q16)*SD + quad*8;
    qH[0] = *(const bfrag8*)(qp);
    qH[1] = *(const bfrag8*)(qp + 32);
    qL[0] = *(const bfrag8*)(qp2);
    qL[1] = *(const bfrag8*)(qp2 + 32);
  }

  float m_row[4], l_row[4];
  f32x4 ctx[4];
  #pragma unroll
  for (int rr=0;rr<4;rr++){ m_row[rr]=-INFINITY; l_row[rr]=0.f; }
  #pragma unroll
  for (int nt=0;nt<4;nt++) ctx[nt] = (f32x4){0.f,0.f,0.f,0.f};

  for (int kt=0; kt<8; ++kt){
    // stage K and V^T (2 issues per wave per slab -> full 64 rows)
    #pragma unroll
    for (int t=0;t<2;t++){
      int br = w*16 + t*8;
      int gr = br + row8;
      size_t gk = base + (size_t)(kt*64+gr)*SD + soff;
      gload16(Kh + gk, &SM[0    + br*64]);
      gload16(Kl + gk, &SM[4096 + br*64]);
      size_t gv = vbase + (size_t)gr*SD + kt*64 + soff;
      gload16(Vth + gv, &SM[8192  + br*64]);
      gload16(Vtl + gv, &SM[12288 + br*64]);
    }
    __syncthreads();

    // scores = Q K^T (bf16x3)
    f32x4 sc[4];
    #pragma unroll
    for (int nt=0;nt<4;nt++) sc[nt] = (f32x4){0.f,0.f,0.f,0.f};
    #pragma unroll
    for (int kk=0;kk<2;kk++){
      int co = ((kk*4+quad) ^ sw)*8;
      #pragma unroll
      for (int nt=0;nt<4;nt++){
        bfrag8 bH = *(const bfrag8*)&SM[0    + (nt*16+q16)*64 + co];
        bfrag8 bL = *(const bfrag8*)&SM[4096 + (nt*16+q16)*64 + co];
        sc[nt] = MFMA_B16(qH[kk],bH,sc[nt]);
        sc[nt] = MFMA_B16(qH[kk],bL,sc[nt]);
        sc[nt] = MFMA_B16(qL[kk],bH,sc[nt]);
      }
    }
    #pragma unroll
    for (int nt=0;nt<4;nt++)
      #pragma unroll
      for (int rr=0;rr<4;rr++) sc[nt][rr] *= 0.125f;

    float alpha[4];
    #pragma unroll
    for (int rr=0;rr<4;rr++){
      float mx = sc[0][rr];
      #pragma unroll
      for (int nt=1;nt<4;nt++) mx = fmaxf(mx, sc[nt][rr]);
      mx = fmaxf(mx, __shfl_xor(mx, 1));
      mx = fmaxf(mx, __shfl_xor(mx, 2));
      mx = fmaxf(mx, __shfl_xor(mx, 4));
      mx = fmaxf(mx, __shfl_xor(mx, 8));
      float nm = fmaxf(m_row[rr], mx);
      alpha[rr] = expf(m_row[rr] - nm);
      m_row[rr] = nm;
    }
    #pragma unroll
    for (int rr=0;rr<4;rr++){
      float S = 0.f;
      #pragma unroll
      for (int nt=0;nt<4;nt++){
        float p = expf(sc[nt][rr] - m_row[rr]);
        sc[nt][rr] = p;
        S += p;
      }
      S += __shfl_xor(S, 1);
      S += __shfl_xor(S, 2);
      S += __shfl_xor(S, 4);
      S += __shfl_xor(S, 8);
      l_row[rr] = l_row[rr]*alpha[rr] + S;
      #pragma unroll
      for (int nt=0;nt<4;nt++) ctx[nt][rr] *= alpha[rr];
    }
    // P -> PS [64][64] chunk-XOR swz (wave-private rows; no barrier needed)
    #pragma unroll
    for (int nt=0;nt<4;nt++){
      int c = nt*2 + (q16>>3);
      #pragma unroll
      for (int rr=0;rr<4;rr++){
        int prow = quad*4 + rr;
        SM[16384 + (w*16+prow)*64 + ((c ^ (prow&7))*8) + (q16&7)] = bf_hi(sc[nt][rr]);
      }
    }

    // ctx += P V  (P plain bf16, V bf16x2)
    #pragma unroll
    for (int kk2=0;kk2<2;kk2++){
      int co2 = ((kk2*4+quad) ^ sw)*8;
      bfrag8 aP = *(const bfrag8*)&SM[16384 + (w*16+q16)*64 + co2];
      #pragma unroll
      for (int nt=0;nt<4;nt++){
        bfrag8 vH = *(const bfrag8*)&SM[8192  + (nt*16+q16)*64 + co2];
        bfrag8 vL = *(const bfrag8*)&SM[12288 + (nt*16+q16)*64 + co2];
        ctx[nt] = MFMA_B16(aP,vH,ctx[nt]);
        ctx[nt] = MFMA_B16(aP,vL,ctx[nt]);
      }
    }
    __syncthreads();
  }
  // epilogue: split and store (Ch/Cl alias Qh/Ql: we overwrite only our own tile)
  #pragma unroll
  for (int rr=0;rr<4;rr++){
    float inv = 1.f / l_row[rr];
    #pragma unroll
    for (int nt=0;nt<4;nt++){
      int s = s0 + w*16 + quad*4 + rr;
      u16t hh, ll; split2(ctx[nt][rr]*inv, hh, ll);
      size_t o = base + (size_t)s*SD + nt*16 + q16;
      Ch[o] = hh; Cl[o] = ll;
    }
  }
}

// ---------- K5: MFMA bf16x3: out = log(sum_j g_j * exp(ctx_j @ Wo[e_j] + bo[e_j])) ----------
// Both operands pre-split; staged via global_load_lds with XOR chunk swizzle.
__global__ __launch_bounds__(256) void k_out(
  const u16t* __restrict__ Ch, const u16t* __restrict__ Cl,
  const u16t* __restrict__ Wth, const u16t* __restrict__ Wtl,
  const float* __restrict__ bo, const int* __restrict__ tk_idx,
  const float* __restrict__ tk_gates, int pair0, float* __restrict__ out)
{
  __shared__ __align__(16) u16t Ah[64*64], Al[64*64];
  __shared__ __align__(16) u16t Bh[64*64], Bl[64*64];   // [f][k]
  int Nb = gridDim.x*gridDim.y*gridDim.z;
  int flat = blockIdx.x + gridDim.x*(blockIdx.y + gridDim.y*blockIdx.z);
  int nf = (flat & 7)*(Nb>>3) + (flat>>3);
  int bxx = nf & 7, byy = (nf>>3) & 7, lb = nf >> 6;
  int gb = (pair0 >> 1) + lb;
  int tid = threadIdx.x;
  int w = tid>>6, lane = tid&63, q16 = lane&15, quad = lane>>4;
  int s0 = byy*64, f0 = bxx*64;
  int row8 = lane>>3, cc = lane&7;
  int soff = (cc ^ row8)*8;
  int sw = q16 & 7;

  f32x4 acc2[2][4];
  #pragma unroll
  for (int j=0;j<2;j++)
    #pragma unroll
    for (int nt=0;nt<4;nt++) acc2[j][nt] = (f32x4){0.f,0.f,0.f,0.f};

  for (int j=0;j<2;++j){
    int e = tk_idx[pair0 + lb*2 + j] & 7;
    const u16t* AH = Ch + (size_t)(lb*2+j)*SDSQ;
    const u16t* AL = Cl + (size_t)(lb*2+j)*SDSQ;
    const u16t* WH = Wth + (size_t)e*SDSQ;
    const u16t* WL = Wtl + (size_t)e*SDSQ;
    for (int k0=0;k0<SD;k0+=64){
      #pragma unroll
      for (int t=0;t<2;t++){
        int br = w*16 + t*8, gr = br + row8;
        size_t ga  = (size_t)(s0+gr)*SD + k0 + soff;
        size_t gbo = (size_t)(f0+gr)*SD + k0 + soff;
        gload16(AH + ga,  &Ah[br*64]);
        gload16(AL + ga,  &Al[br*64]);
        gload16(WH + gbo, &Bh[br*64]);
        gload16(WL + gbo, &Bl[br*64]);
      }
      __syncthreads();
      #pragma unroll
      for (int kk=0;kk<2;kk++){
        int co = ((kk*4+quad) ^ sw)*8;
        bfrag8 aH = *(const bfrag8*)&Ah[(w*16+q16)*64 + co];
        bfrag8 aL = *(const bfrag8*)&Al[(w*16+q16)*64 + co];
        #pragma unroll
        for (int nt=0;nt<4;nt++){
          bfrag8 bH = *(const bfrag8*)&Bh[(nt*16+q16)*64 + co];
          bfrag8 bL = *(const bfrag8*)&Bl[(nt*16+q16)*64 + co];
          acc2[j][nt] = MFMA_B16(aH,bH,acc2[j][nt]);
          acc2[j][nt] = MFMA_B16(aH,bL,acc2[j][nt]);
          acc2[j][nt] = MFMA_B16(aL,bH,acc2[j][nt]);
        }
      }
      __syncthreads();
    }
  }
  int e0 = tk_idx[pair0 + lb*2 + 0] & 7, e1 = tk_idx[pair0 + lb*2 + 1] & 7;
  float g0 = tk_gates[pair0 + lb*2 + 0], g1 = tk_gates[pair0 + lb*2 + 1];
  #pragma unroll
  for (int nt=0;nt<4;nt++){
    #pragma unroll
    for (int rr=0;rr<4;rr++){
      int s = s0 + w*16 + quad*4 + rr;
      int f = f0 + nt*16 + q16;
      float o0 = acc2[0][nt][rr] + bo[e0*SD+f];
      float o1 = acc2[1][nt][rr] + bo[e1*SD+f];
      float cmb = g0*expf(o0) + g1*expf(o1);
      if (cmb == 0.f) cmb = 2.2204460492503131e-16f;
      out[(size_t)gb*SDSQ + (size_t)s*SD + f] = logf(cmb);
    }
  }
}

extern "C" void kernel_launch(void* const* d_in, const int* in_sizes, int n_in,
                              void* d_out, int out_size, void* d_ws, size_t ws_size,
                              hipStream_t stream)
{
  const float* q  = (const float*)d_in[0];
  const float* k  = (const float*)d_in[1];
  const float* v  = (const float*)d_in[2];
  const float* wg = (const float*)d_in[4];
  const float* wn = (const float*)d_in[5];
  const float* Wq = (const float*)d_in[6];
  const float* bq = (const float*)d_in[7];
  const float* Wk = (const float*)d_in[8];
  const float* bk = (const float*)d_in[9];
  const float* Wv = (const float*)d_in[10];
  const float* bv = (const float*)d_in[11];
  const float* Wo = (const float*)d_in[12];
  const float* bo = (const float*)d_in[13];
  float* out = (float*)d_out;

  char* ws = (char*)d_ws;
  double* xs      = (double*)(ws + 0);
  int*   tk_idx   = (int*)  (ws + 131072);
  float* tk_gates = (float*)(ws + 131072 + 256);

  const size_t header = (size_t)1 << 20;
  const size_t XSB = (size_t)32 * SDSQ * 2;   // 16 MiB: one hi or lo slab of q/k/v
  const size_t WSB = (size_t)8  * SDSQ * 2;   // 4 MiB:  one hi or lo slab of a weight set
  u16t* qch = (u16t*)(ws + header + 0*XSB);
  u16t* qcl = (u16t*)(ws + header + 1*XSB);
  u16t* kh_ = (u16t*)(ws + header + 2*XSB);
  u16t* kl_ = (u16t*)(ws + header + 3*XSB);
  u16t* vh_ = (u16t*)(ws + header + 4*XSB);
  u16t* vl_ = (u16t*)(ws + header + 5*XSB);
  char* wbase = ws + header + 6*XSB;
  u16t* wqh = (u16t*)(wbase + 0*WSB);
  u16t* wql = (u16t*)(wbase + 1*WSB);
  u16t* wkh = (u16t*)(wbase + 2*WSB);
  u16t* wkl = (u16t*)(wbase + 3*WSB);
  u16t* wvh = (u16t*)(wbase + 4*WSB);
  u16t* wvl = (u16t*)(wbase + 5*WSB);
  u16t* woh = (u16t*)(wbase + 6*WSB);
  u16t* wol = (u16t*)(wbase + 7*WSB);
  char* bufbase = wbase + 8*WSB;

  const size_t slab = (size_t)SDSQ * 2;       // 0.5 MiB per pair per slab; 6 slabs/pair
  size_t used = (size_t)(bufbase - ws);
  size_t avail = (ws_size > used) ? (ws_size - used) : 0;
  int CH = (int)(avail / (6 * slab));
  CH &= ~1;
  if (CH > 64) CH = 64;
  if (CH < 2)  CH = 2;

  // pre-pass: split inputs, split+transpose weights
  k_cvt_x<<<dim3(8192), dim3(256), 0, stream>>>(q, qch, qcl, 1);
  k_cvt_x<<<dim3(8192), dim3(256), 0, stream>>>(k, kh_, kl_, 0);
  k_cvt_x<<<dim3(8192), dim3(256), 0, stream>>>(v, vh_, vl_, 0);
  k_cvt_w<<<dim3(8,8,8), dim3(256), 0, stream>>>(Wq, wqh, wql);
  k_cvt_w<<<dim3(8,8,8), dim3(256), 0, stream>>>(Wk, wkh, wkl);
  k_cvt_w<<<dim3(8,8,8), dim3(256), 0, stream>>>(Wv, wvh, wvl);
  k_cvt_w<<<dim3(8,8,8), dim3(256), 0, stream>>>(Wo, woh, wol);

  k_xs  <<<dim3(32), dim3(512), 0, stream>>>(q, xs);
  k_gate<<<dim3(1), dim3(256), 0, stream>>>(xs, wg, wn, tk_idx, tk_gates,
                                            out + (size_t)out_size - 1);

  for (int pair0 = 0; pair0 < 64; pair0 += CH){
    int cur = (64 - pair0 < CH) ? (64 - pair0) : CH;
    u16t* Qh  = (u16t*)bufbase;
    u16t* Ql  = Qh  + (size_t)CH * SDSQ;
    u16t* Kh  = Ql  + (size_t)CH * SDSQ;
    u16t* Kl  = Kh  + (size_t)CH * SDSQ;
    u16t* Vth = Kl  + (size_t)CH * SDSQ;
    u16t* Vtl = Vth + (size_t)CH * SDSQ;
    u16t* Ch = Qh;   // ctx in-place over Q slabs
    u16t* Cl = Ql;

    k_proj<<<dim3(4,4,cur*3), dim3(256), 0, stream>>>(
        qch,qcl, kh_,kl_, vh_,vl_, wqh,wql, wkh,wkl, wvh,wvl,
        bq,bk,bv, tk_idx, pair0, Qh,Ql, Kh,Kl, Vth,Vtl);
    k_attn<<<dim3(8,8,cur), dim3(256), 0, stream>>>(Qh,Ql, Kh,Kl, Vth,Vtl, Ch,Cl);
    k_out <<<dim3(8,8,cur/2), dim3(256), 0, stream>>>(Ch,Cl, woh,wol, bo, tk_idx, tk_gates,
                                                      pair0, out);
  }
}

// Round 7
// 697.229 us; speedup vs baseline: 1.3804x; 1.0925x over previous
//
#include <hip/hip_runtime.h>
#include <math.h>

typedef unsigned int u32;
typedef unsigned long long u64;
typedef unsigned short u16t;

#define SD   512
#define EE   8
#define DH   64
#define SDSQ (512*512)
#define LDSW 72   // padded LDS row stride (used by k_cvt_w staging)

#define QSC  0.18033688011112042f   // 0.125 * log2(e): folds attn scale + exp->exp2
#define LOG2E 1.4426950408889634f
#define LN2   0.6931471805599453f

typedef __attribute__((ext_vector_type(8))) short bfrag8;
typedef __attribute__((ext_vector_type(4))) float f32x4;
typedef __attribute__((ext_vector_type(8))) unsigned short u16x8;

typedef const __attribute__((address_space(1))) void gas_void;
typedef __attribute__((address_space(3))) void las_void;

#define MFMA_B16(a,b,c) __builtin_amdgcn_mfma_f32_16x16x32_bf16((a),(b),(c),0,0,0)

__device__ __forceinline__ u32 rotl32(u32 x, int r){ return (x<<r)|(x>>(32-r)); }

__device__ __forceinline__ u16t bf_hi(float a){
  u32 x; __builtin_memcpy(&x,&a,4);
  u32 r = x + 0x7fffu + ((x>>16)&1u);
  return (u16t)(r>>16);
}
__device__ __forceinline__ float bf_f(u16t h){
  u32 x = ((u32)h)<<16; float f; __builtin_memcpy(&f,&x,4); return f;
}
__device__ __forceinline__ void split2(float a, u16t& h, u16t& l){
  h = bf_hi(a);
  l = bf_hi(a - bf_f(h));
}

// async global->LDS, 16B per lane; LDS dest is wave-uniform base + lane*16
__device__ __forceinline__ void gload16(const u16t* g, u16t* l){
  __builtin_amdgcn_global_load_lds((gas_void*)g, (las_void*)l, 16, 0, 0);
}

// threefry2x32, key = (0, 42)
__device__ __forceinline__ void threefry_0_42(u32 x0, u32 x1, u32& o0, u32& o1){
  const u32 k0=0u, k1=42u;
  const u32 ks2 = k0 ^ k1 ^ 0x1BD11BDAu;
  const int R0[4]={13,15,26,6}, R1[4]={17,29,16,24};
  x0 += k0; x1 += k1;
  #pragma unroll
  for(int r=0;r<4;r++){ x0+=x1; x1=rotl32(x1,R0[r]); x1^=x0; }
  x0+=k1; x1+=ks2+1u;
  #pragma unroll
  for(int r=0;r<4;r++){ x0+=x1; x1=rotl32(x1,R1[r]); x1^=x0; }
  x0+=ks2; x1+=k0+2u;
  #pragma unroll
  for(int r=0;r<4;r++){ x0+=x1; x1=rotl32(x1,R0[r]); x1^=x0; }
  x0+=k0; x1+=k1+3u;
  #pragma unroll
  for(int r=0;r<4;r++){ x0+=x1; x1=rotl32(x1,R1[r]); x1^=x0; }
  x0+=k1; x1+=ks2+4u;
  #pragma unroll
  for(int r=0;r<4;r++){ x0+=x1; x1=rotl32(x1,R0[r]); x1^=x0; }
  x0+=ks2; x1+=k0+5u;
  o0 = x0; o1 = x1;
}

__device__ double erfinv64(double x){
  double w = -log((1.0 - x) * (1.0 + x));
  double p;
  if (w < 5.0){
    w = w - 2.5;
    p = 2.81022636e-08;
    p = 3.43273939e-07 + p*w;
    p = -3.5233877e-06 + p*w;
    p = -4.39150654e-06 + p*w;
    p = 0.00021858087  + p*w;
    p = -0.00125372503 + p*w;
    p = -0.00417768164 + p*w;
    p = 0.246640727    + p*w;
    p = 1.50140941     + p*w;
  } else {
    w = sqrt(w) - 3.0;
    p = -0.000200214257;
    p = 0.000100950558 + p*w;
    p = 0.00134934322  + p*w;
    p = -0.00367342844 + p*w;
    p = 0.00573950773  + p*w;
    p = -0.0076224613  + p*w;
    p = 0.00943887047  + p*w;
    p = 1.00167406     + p*w;
    p = 2.83297682     + p*w;
  }
  double r = p * x;
  #pragma unroll
  for (int it=0; it<2; ++it){
    double e = erf(r) - x;
    r -= e / (1.1283791670955126 * exp(-r*r));
  }
  return r;
}

__device__ double jax_noise_part32(int i){
  u32 o0, o1;
  threefry_0_42(0u, (u32)i, o0, o1);
  u32 bits = o0 ^ o1;
  u32 fb = (bits >> 9) | 0x3f800000u;
  float f; __builtin_memcpy(&f, &fb, 4);
  f -= 1.0f;
  u32 lob = 0xBF7FFFFFu;
  float lo; __builtin_memcpy(&lo, &lob, 4);
  float t = f * 2.0f;
  float u = t + lo;
  u = fmaxf(u, lo);
  return 1.4142135623730951 * erfinv64((double)u);
}

// ---------- P0a: fp32 -> bf16 hi/lo (optionally NaN-clean), layout-preserving ----------
__global__ __launch_bounds__(256) void k_cvt_x(
  const float* __restrict__ src, u16t* __restrict__ dh, u16t* __restrict__ dl, int clean)
{
  const int n4 = 32*SDSQ/4;
  int i = blockIdx.x*256 + threadIdx.x;
  if (i >= n4) return;
  float4 r = ((const float4*)src)[i];
  float a[4] = {r.x, r.y, r.z, r.w};
  if (clean){
    #pragma unroll
    for (int u=0;u<4;u++) if (isnan(a[u])) a[u] = 0.f;
  }
  u16t h[4], l[4];
  #pragma unroll
  for (int u=0;u<4;u++) split2(a[u], h[u], l[u]);
  ((ushort4*)dh)[i] = make_ushort4(h[0],h[1],h[2],h[3]);
  ((ushort4*)dl)[i] = make_ushort4(l[0],l[1],l[2],l[3]);
}

// ---------- P0b: W[e][k][f] fp32 -> Wt[e][f][k] bf16 hi/lo (transpose + split) ----------
__global__ __launch_bounds__(256) void k_cvt_w(
  const float* __restrict__ W, u16t* __restrict__ th, u16t* __restrict__ tl)
{
  __shared__ u16t Th[64*LDSW], Tl[64*LDSW];
  int e = blockIdx.z;
  int k0 = blockIdx.y*64, f0 = blockIdx.x*64;
  int tid = threadIdx.x;
  int r = tid>>2, c4 = (tid&3)*16;
  const float* Wp = W + (size_t)e*SDSQ + (size_t)(k0+r)*SD + f0 + c4;
  #pragma unroll
  for (int i=0;i<4;i++){
    float4 rv = *(const float4*)(Wp + 4*i);
    float a[4]={rv.x,rv.y,rv.z,rv.w};
    #pragma unroll
    for (int u=0;u<4;u++){
      u16t h,l; split2(a[u],h,l);
      Th[(c4+4*i+u)*LDSW + r] = h;
      Tl[(c4+4*i+u)*LDSW + r] = l;
    }
  }
  __syncthreads();
  u16t* dh = th + (size_t)e*SDSQ + (size_t)(f0+r)*SD + k0 + c4;
  u16t* dl = tl + (size_t)e*SDSQ + (size_t)(f0+r)*SD + k0 + c4;
  *(u16x8*)dh     = *(const u16x8*)&Th[r*LDSW + c4];
  *(u16x8*)(dh+8) = *(const u16x8*)&Th[r*LDSW + c4 + 8];
  *(u16x8*)dl     = *(const u16x8*)&Tl[r*LDSW + c4];
  *(u16x8*)(dl+8) = *(const u16x8*)&Tl[r*LDSW + c4 + 8];
}

// ---------- K1: xs[b][d] = sum_s nan_to_zero(q[b][s][d])  (f64 accum) ----------
__global__ void k_xs(const float* __restrict__ q, double* __restrict__ xs){
  int b = blockIdx.x, d = blockIdx.y*128 + threadIdx.x;
  const float* p = q + (size_t)b*SDSQ + d;
  double acc = 0.0;
  for (int s=0; s<SD; ++s){
    float f = p[(size_t)s*SD];
    if (!isnan(f)) acc += (double)f;
  }
  xs[b*SD + d] = acc;
}

// ---------- K2: gating in f64 ----------
__global__ __launch_bounds__(256) void k_gate(
    const double* __restrict__ xs, const float* __restrict__ wg,
    const float* __restrict__ wn, int* __restrict__ tk_idx,
    float* __restrict__ tk_gates, float* __restrict__ out_loss)
{
  __shared__ double cl_s[256], sd_s[256], nz_s[256], pr_s[256];
  __shared__ double thrI_s[32], thrO_s[32], g0_s[32], g1_s[32];
  __shared__ int i0_s[32], i1_s[32];
  int tid = threadIdx.x;
  int b = tid >> 3, e = tid & 7;
  double c=0.0, n=0.0;
  const double* xr = xs + b*SD;
  for (int d=0; d<SD; ++d){
    double x = xr[d];
    c += x * (double)wg[d*EE + e];
    n += x * (double)wn[d*EE + e];
  }
  double sp = fmax(n, 0.0) + log1p(exp(-fabs(n)));
  double sdv = sp + 0.01;
  double nz = c + jax_noise_part32(tid) * sdv;
  cl_s[tid]=c; sd_s[tid]=sdv; nz_s[tid]=nz;
  __syncthreads();
  if (tid < 32){
    int bb = tid;
    double v0=-INFINITY,v1=-INFINITY,v2=-INFINITY; int i0=0,i1=0;
    for (int ee=0; ee<8; ++ee){
      double vv = nz_s[bb*8+ee];
      if (vv > v0){ v2=v1; v1=v0;i1=i0; v0=vv;i0=ee; }
      else if (vv > v1){ v2=v1; v1=vv;i1=ee; }
      else if (vv > v2){ v2=vv; }
    }
    double e1 = exp(v1 - v0);
    double s = 1.0 + e1;
    double g0 = 1.0/s + 1e-9, g1 = e1/s + 1e-9;
    tk_idx[bb*2+0]=i0; tk_idx[bb*2+1]=i1;
    tk_gates[bb*2+0]=(float)g0; tk_gates[bb*2+1]=(float)g1;
    i0_s[bb]=i0; i1_s[bb]=i1; g0_s[bb]=g0; g1_s[bb]=g1;
    thrI_s[bb]=v2; thrO_s[bb]=v1;
  }
  __syncthreads();
  {
    double thrI = thrI_s[b], thrO = thrO_s[b];
    bool isin = nz_s[tid] > thrI;
    double t = (cl_s[tid] - (isin ? thrI : thrO)) / sd_s[tid];
    pr_s[tid] = 0.5 * (1.0 + erf(t * 0.7071067811865476));
  }
  __syncthreads();
  if (tid == 0){
    double imp[8], ld[8];
    for (int i=0;i<8;i++){ imp[i]=0.0; ld[i]=0.0; }
    for (int bb=0; bb<32; ++bb){
      imp[i0_s[bb]] += g0_s[bb];
      imp[i1_s[bb]] += g1_s[bb];
    }
    for (int i=0;i<256;i++) ld[i&7] += pr_s[i];
    double loss = 0.0;
    for (int a=0;a<2;a++){
      double* arr = a ? ld : imp;
      double mu=0.0; for(int i=0;i<8;i++) mu += arr[i]; mu *= 0.125;
      double var=0.0; for(int i=0;i<8;i++){ double dd=arr[i]-mu; var += dd*dd; }
      var *= (1.0/7.0);
      loss += var / (mu*mu + 1e-10);
    }
    loss *= 0.01;
    out_loss[0] = (float)loss;
  }
}

// ---------- K3: MFMA bf16x3 GEMM  Y = X @ W[e] + bias[e] ----------
// 128x128 tile, BK=64, 4 waves (2x2), global_load_lds staging with XOR chunk swizzle.
// Outputs PRE-SPLIT (hi/lo bf16). m==0 (Q) output is additionally scaled by
// QSC = 0.125*log2(e) so k_attn's scores come out in the log2 domain.
// m==2 (V) output is written TRANSPOSED (Vt[d][s]) via swapped operand roles.
__global__ __launch_bounds__(256) void k_proj(
  const u16t* __restrict__ qh, const u16t* __restrict__ ql,
  const u16t* __restrict__ kh, const u16t* __restrict__ kl,
  const u16t* __restrict__ vh, const u16t* __restrict__ vl,
  const u16t* __restrict__ wqh, const u16t* __restrict__ wql,
  const u16t* __restrict__ wkh, const u16t* __restrict__ wkl,
  const u16t* __restrict__ wvh, const u16t* __restrict__ wvl,
  const float* __restrict__ bq, const float* __restrict__ bk, const float* __restrict__ bv,
  const int* __restrict__ tk_idx, int pair0,
  u16t* __restrict__ Qh, u16t* __restrict__ Ql,
  u16t* __restrict__ Kh, u16t* __restrict__ Kl,
  u16t* __restrict__ Vth, u16t* __restrict__ Vtl)
{
  // SM regions (elems): A_hi @0, A_lo @8192, B_hi @16384, B_lo @24576
  __shared__ __align__(16) u16t SM[4*128*64];
  int Nb = gridDim.x*gridDim.y*gridDim.z;
  int flat = blockIdx.x + gridDim.x*(blockIdx.y + gridDim.y*blockIdx.z);
  int nf = (flat & 7)*(Nb>>3) + (flat>>3);
  int bxx = nf & 3, byy = (nf>>2) & 3, z = nf >> 4;
  int lp = z/3, m = z - lp*3;
  int gp = pair0 + lp;
  int b = gp >> 1;
  int e = tk_idx[gp] & 7;
  const u16t *Xh, *Xl, *Wh, *Wl; const float* bias; u16t *Yh, *Yl;
  if (m==0){ Xh=qh; Xl=ql; Wh=wqh; Wl=wql; bias=bq; Yh=Qh;  Yl=Ql;  }
  else if (m==1){ Xh=kh; Xl=kl; Wh=wkh; Wl=wkl; bias=bk; Yh=Kh;  Yl=Kl;  }
  else { Xh=vh; Xl=vl; Wh=wvh; Wl=wvl; bias=bv; Yh=Vth; Yl=Vtl; }
  bool tr = (m==2);
  float ysc = (m==0) ? QSC : 1.0f;
  Xh += (size_t)b*SDSQ; Xl += (size_t)b*SDSQ;
  Wh += (size_t)e*SDSQ; Wl += (size_t)e*SDSQ;
  bias += e*SD;
  Yh += (size_t)lp*SDSQ; Yl += (size_t)lp*SDSQ;

  int tid = threadIdx.x, w = tid>>6, lane = tid&63;
  int q16 = lane&15, quad = lane>>4;
  int wm = w>>1, wnn = w&1;
  int s0 = byy*128, f0 = bxx*128;
  int row8 = lane>>3, cc = lane&7;
  int soff = (cc ^ row8)*8;          // inverse-swizzled source chunk (rule #21)
  int sw = q16 & 7;                  // read-side swizzle key (= row&7 of frag row)
  int aH_off = tr ? 16384 : 0;       // A operand = output-row operand
  int bH_off = tr ? 0 : 16384;

  f32x4 acc[4][4];
  #pragma unroll
  for (int i=0;i<4;i++)
    #pragma unroll
    for (int j=0;j<4;j++) acc[i][j] = (f32x4){0.f,0.f,0.f,0.f};

  for (int k0=0;k0<SD;k0+=64){
    #pragma unroll
    for (int t=0;t<4;t++){
      int br = w*32 + t*8;
      int gr = br + row8;
      size_t ga  = (size_t)(s0+gr)*SD + k0 + soff;
      size_t gbo = (size_t)(f0+gr)*SD + k0 + soff;
      gload16(Xh + ga,  &SM[0     + br*64]);
      gload16(Xl + ga,  &SM[8192  + br*64]);
      gload16(Wh + gbo, &SM[16384 + br*64]);
      gload16(Wl + gbo, &SM[24576 + br*64]);
    }
    __syncthreads();
    #pragma unroll
    for (int kk=0;kk<2;kk++){
      int ch = kk*4 + quad;
      int co = (ch ^ sw)*8;          // swizzled read chunk
      bfrag8 fAH[4], fAL[4], fBH[4], fBL[4];
      #pragma unroll
      for (int i=0;i<4;i++){
        int ra = wm*64  + i*16 + q16;
        int rb = wnn*64 + i*16 + q16;
        fAH[i] = *(const bfrag8*)&SM[aH_off        + ra*64 + co];
        fAL[i] = *(const bfrag8*)&SM[aH_off + 8192 + ra*64 + co];
        fBH[i] = *(const bfrag8*)&SM[bH_off        + rb*64 + co];
        fBL[i] = *(const bfrag8*)&SM[bH_off + 8192 + rb*64 + co];
      }
      #pragma unroll
      for (int i=0;i<4;i++)
        #pragma unroll
        for (int j=0;j<4;j++){
          acc[i][j] = MFMA_B16(fAH[i], fBH[j], acc[i][j]);
          acc[i][j] = MFMA_B16(fAH[i], fBL[j], acc[i][j]);
          acc[i][j] = MFMA_B16(fAL[i], fBH[j], acc[i][j]);
        }
    }
    __syncthreads();
  }
  if (!tr){
    #pragma unroll
    for (int i=0;i<4;i++){
      #pragma unroll
      for (int j=0;j<4;j++){
        int f = f0 + wnn*64 + j*16 + q16;
        float bb = bias[f];
        #pragma unroll
        for (int rr=0;rr<4;rr++){
          int s = s0 + wm*64 + i*16 + quad*4 + rr;
          u16t hh, ll; split2((acc[i][j][rr] + bb)*ysc, hh, ll);
          size_t o = (size_t)s*SD + f;
          Yh[o] = hh; Yl[o] = ll;
        }
      }
    }
  } else {
    #pragma unroll
    for (int i=0;i<4;i++){
      #pragma unroll
      for (int rr=0;rr<4;rr++){
        int fr = f0 + wm*64 + i*16 + quad*4 + rr;
        float bb = bias[fr];
        #pragma unroll
        for (int j=0;j<4;j++){
          int scol = s0 + wnn*64 + j*16 + q16;
          u16t hh, ll; split2(acc[i][j][rr] + bb, hh, ll);
          size_t o = (size_t)fr*SD + scol;
          Yh[o] = hh; Yl[o] = ll;
        }
      }
    }
  }
}

// ---------- K4: MFMA flash attention per (pair, head, q-tile 64) ----------
// Q pre-scaled by 0.125*log2(e): scores arrive in log2 domain; softmax uses
// hardware exp2 + defer-max (THR=8). Q fragments in registers; K/V^T staged via
// global_load_lds + XOR chunk swizzle; PS wave-private. LDS 40 KB -> 4 blocks/CU.
__global__ __launch_bounds__(256, 4) void k_attn(
  const u16t* __restrict__ Qh, const u16t* __restrict__ Ql,
  const u16t* __restrict__ Kh, const u16t* __restrict__ Kl,
  const u16t* __restrict__ Vth, const u16t* __restrict__ Vtl,
  u16t* __restrict__ Ch, u16t* __restrict__ Cl)
{
  // elems: KH@0, KL@4096, VTH@8192, VTL@12288, PS@16384 ([64][64] swz)
  __shared__ __align__(16) u16t SM[20480];
  int tid = threadIdx.x;
  int w = tid>>6, lane = tid&63, q16 = lane&15, quad = lane>>4;
  int Nb = gridDim.x*gridDim.y*gridDim.z;
  int flat = blockIdx.x + gridDim.x*(blockIdx.y + gridDim.y*blockIdx.z);
  int nf = (flat & 7)*(Nb>>3) + (flat>>3);
  int qt = nf & 7, h = (nf>>3) & 7, lp = nf >> 6;
  int s0 = qt*64;
  const size_t base  = (size_t)lp*SDSQ + h*DH;             // [s][512] slabs
  const size_t vbase = (size_t)lp*SDSQ + (size_t)h*DH*SD;  // Vt [d][512]
  int row8 = lane>>3, cc = lane&7;
  int soff = (cc ^ row8)*8;
  int sw = q16 & 7;

  // Q fragments -> registers (rows s0 + w*16 + q16, cols kk*32 + quad*8)
  bfrag8 qH[2], qL[2];
  {
    const u16t* qp  = Qh + base + (size_t)(s0 + w*16 + q16)*SD + quad*8;
    const u16t* qp2 = Ql + base + (size_t)(s0 + w*16 + q16)*SD + quad*8;
    qH[0] = *(const bfrag8*)(qp);
    qH[1] = *(const bfrag8*)(qp + 32);
    qL[0] = *(const bfrag8*)(qp2);
    qL[1] = *(const bfrag8*)(qp2 + 32);
  }

  float m_row[4], l_row[4];
  f32x4 ctx[4];
  #pragma unroll
  for (int rr=0;rr<4;rr++){ m_row[rr]=-INFINITY; l_row[rr]=0.f; }
  #pragma unroll
  for (int nt=0;nt<4;nt++) ctx[nt] = (f32x4){0.f,0.f,0.f,0.f};

  for (int kt=0; kt<8; ++kt){
    // stage K and V^T (2 issues per wave per slab -> full 64 rows)
    #pragma unroll
    for (int t=0;t<2;t++){
      int br = w*16 + t*8;
      int gr = br + row8;
      size_t gk = base + (size_t)(kt*64+gr)*SD + soff;
      gload16(Kh + gk, &SM[0    + br*64]);
      gload16(Kl + gk, &SM[4096 + br*64]);
      size_t gv = vbase + (size_t)gr*SD + kt*64 + soff;
      gload16(Vth + gv, &SM[8192  + br*64]);
      gload16(Vtl + gv, &SM[12288 + br*64]);
    }
    __syncthreads();

    // scores (log2 domain) = (Q*QSC) K^T  (bf16x3)
    f32x4 sc[4];
    #pragma unroll
    for (int nt=0;nt<4;nt++) sc[nt] = (f32x4){0.f,0.f,0.f,0.f};
    #pragma unroll
    for (int kk=0;kk<2;kk++){
      int co = ((kk*4+quad) ^ sw)*8;
      #pragma unroll
      for (int nt=0;nt<4;nt++){
        bfrag8 bH = *(const bfrag8*)&SM[0    + (nt*16+q16)*64 + co];
        bfrag8 bL = *(const bfrag8*)&SM[4096 + (nt*16+q16)*64 + co];
        sc[nt] = MFMA_B16(qH[kk],bH,sc[nt]);
        sc[nt] = MFMA_B16(qH[kk],bL,sc[nt]);
        sc[nt] = MFMA_B16(qL[kk],bH,sc[nt]);
      }
    }

    // online softmax in log2 domain with defer-max (THR=8)
    float mx4[4];
    bool grow = false;
    #pragma unroll
    for (int rr=0;rr<4;rr++){
      float mx = sc[0][rr];
      #pragma unroll
      for (int nt=1;nt<4;nt++) mx = fmaxf(mx, sc[nt][rr]);
      mx = fmaxf(mx, __shfl_xor(mx, 1));
      mx = fmaxf(mx, __shfl_xor(mx, 2));
      mx = fmaxf(mx, __shfl_xor(mx, 4));
      mx = fmaxf(mx, __shfl_xor(mx, 8));
      mx4[rr] = mx;
      grow = grow || (mx > m_row[rr] + 8.f);
    }
    if (__any(grow ? 1 : 0)){
      #pragma unroll
      for (int rr=0;rr<4;rr++){
        float nm = fmaxf(m_row[rr], mx4[rr]);
        float al = exp2f(m_row[rr] - nm);
        m_row[rr] = nm;
        l_row[rr] *= al;
        #pragma unroll
        for (int nt=0;nt<4;nt++) ctx[nt][rr] *= al;
      }
    }
    #pragma unroll
    for (int rr=0;rr<4;rr++){
      float S = 0.f;
      #pragma unroll
      for (int nt=0;nt<4;nt++){
        float p = exp2f(sc[nt][rr] - m_row[rr]);
        sc[nt][rr] = p;
        S += p;
      }
      S += __shfl_xor(S, 1);
      S += __shfl_xor(S, 2);
      S += __shfl_xor(S, 4);
      S += __shfl_xor(S, 8);
      l_row[rr] += S;
    }
    // P -> PS [64][64] chunk-XOR swz (wave-private rows; no barrier needed)
    #pragma unroll
    for (int nt=0;nt<4;nt++){
      int c = nt*2 + (q16>>3);
      #pragma unroll
      for (int rr=0;rr<4;rr++){
        int prow = quad*4 + rr;
        SM[16384 + (w*16+prow)*64 + ((c ^ (prow&7))*8) + (q16&7)] = bf_hi(sc[nt][rr]);
      }
    }

    // ctx += P V  (P plain bf16, V bf16x2)
    #pragma unroll
    for (int kk2=0;kk2<2;kk2++){
      int co2 = ((kk2*4+quad) ^ sw)*8;
      bfrag8 aP = *(const bfrag8*)&SM[16384 + (w*16+q16)*64 + co2];
      #pragma unroll
      for (int nt=0;nt<4;nt++){
        bfrag8 vH = *(const bfrag8*)&SM[8192  + (nt*16+q16)*64 + co2];
        bfrag8 vL = *(const bfrag8*)&SM[12288 + (nt*16+q16)*64 + co2];
        ctx[nt] = MFMA_B16(aP,vH,ctx[nt]);
        ctx[nt] = MFMA_B16(aP,vL,ctx[nt]);
      }
    }
    __syncthreads();
  }
  // epilogue: split and store (Ch/Cl alias Qh/Ql: we overwrite only our own tile)
  #pragma unroll
  for (int rr=0;rr<4;rr++){
    float inv = 1.f / l_row[rr];
    #pragma unroll
    for (int nt=0;nt<4;nt++){
      int s = s0 + w*16 + quad*4 + rr;
      u16t hh, ll; split2(ctx[nt][rr]*inv, hh, ll);
      size_t o = base + (size_t)s*SD + nt*16 + q16;
      Ch[o] = hh; Cl[o] = ll;
    }
  }
}

// ---------- K5: MFMA bf16x3: out = log(sum_j g_j * exp(ctx_j @ Wo[e_j] + bo[e_j])) ----------
// Both operands pre-split; staged via global_load_lds with XOR chunk swizzle.
__global__ __launch_bounds__(256) void k_out(
  const u16t* __restrict__ Ch, const u16t* __restrict__ Cl,
  const u16t* __restrict__ Wth, const u16t* __restrict__ Wtl,
  const float* __restrict__ bo, const int* __restrict__ tk_idx,
  const float* __restrict__ tk_gates, int pair0, float* __restrict__ out)
{
  __shared__ __align__(16) u16t Ah[64*64], Al[64*64];
  __shared__ __align__(16) u16t Bh[64*64], Bl[64*64];   // [f][k]
  int Nb = gridDim.x*gridDim.y*gridDim.z;
  int flat = blockIdx.x + gridDim.x*(blockIdx.y + gridDim.y*blockIdx.z);
  int nf = (flat & 7)*(Nb>>3) + (flat>>3);
  int bxx = nf & 7, byy = (nf>>3) & 7, lb = nf >> 6;
  int gb = (pair0 >> 1) + lb;
  int tid = threadIdx.x;
  int w = tid>>6, lane = tid&63, q16 = lane&15, quad = lane>>4;
  int s0 = byy*64, f0 = bxx*64;
  int row8 = lane>>3, cc = lane&7;
  int soff = (cc ^ row8)*8;
  int sw = q16 & 7;

  f32x4 acc2[2][4];
  #pragma unroll
  for (int j=0;j<2;j++)
    #pragma unroll
    for (int nt=0;nt<4;nt++) acc2[j][nt] = (f32x4){0.f,0.f,0.f,0.f};

  for (int j=0;j<2;++j){
    int e = tk_idx[pair0 + lb*2 + j] & 7;
    const u16t* AH = Ch + (size_t)(lb*2+j)*SDSQ;
    const u16t* AL = Cl + (size_t)(lb*2+j)*SDSQ;
    const u16t* WH = Wth + (size_t)e*SDSQ;
    const u16t* WL = Wtl + (size_t)e*SDSQ;
    for (int k0=0;k0<SD;k0+=64){
      #pragma unroll
      for (int t=0;t<2;t++){
        int br = w*16 + t*8, gr = br + row8;
        size_t ga  = (size_t)(s0+gr)*SD + k0 + soff;
        size_t gbo = (size_t)(f0+gr)*SD + k0 + soff;
        gload16(AH + ga,  &Ah[br*64]);
        gload16(AL + ga,  &Al[br*64]);
        gload16(WH + gbo, &Bh[br*64]);
        gload16(WL + gbo, &Bl[br*64]);
      }
      __syncthreads();
      #pragma unroll
      for (int kk=0;kk<2;kk++){
        int co = ((kk*4+quad) ^ sw)*8;
        bfrag8 aH = *(const bfrag8*)&Ah[(w*16+q16)*64 + co];
        bfrag8 aL = *(const bfrag8*)&Al[(w*16+q16)*64 + co];
        #pragma unroll
        for (int nt=0;nt<4;nt++){
          bfrag8 bH = *(const bfrag8*)&Bh[(nt*16+q16)*64 + co];
          bfrag8 bL = *(const bfrag8*)&Bl[(nt*16+q16)*64 + co];
          acc2[j][nt] = MFMA_B16(aH,bH,acc2[j][nt]);
          acc2[j][nt] = MFMA_B16(aH,bL,acc2[j][nt]);
          acc2[j][nt] = MFMA_B16(aL,bH,acc2[j][nt]);
        }
      }
      __syncthreads();
    }
  }
  int e0 = tk_idx[pair0 + lb*2 + 0] & 7, e1 = tk_idx[pair0 + lb*2 + 1] & 7;
  float g0 = tk_gates[pair0 + lb*2 + 0], g1 = tk_gates[pair0 + lb*2 + 1];
  #pragma unroll
  for (int nt=0;nt<4;nt++){
    #pragma unroll
    for (int rr=0;rr<4;rr++){
      int s = s0 + w*16 + quad*4 + rr;
      int f = f0 + nt*16 + q16;
      float o0 = acc2[0][nt][rr] + bo[e0*SD+f];
      float o1 = acc2[1][nt][rr] + bo[e1*SD+f];
      float cmb = g0*exp2f(o0*LOG2E) + g1*exp2f(o1*LOG2E);
      if (cmb == 0.f) cmb = 2.2204460492503131e-16f;
      out[(size_t)gb*SDSQ + (size_t)s*SD + f] = log2f(cmb)*LN2;
    }
  }
}

extern "C" void kernel_launch(void* const* d_in, const int* in_sizes, int n_in,
                              void* d_out, int out_size, void* d_ws, size_t ws_size,
                              hipStream_t stream)
{
  const float* q  = (const float*)d_in[0];
  const float* k  = (const float*)d_in[1];
  const float* v  = (const float*)d_in[2];
  const float* wg = (const float*)d_in[4];
  const float* wn = (const float*)d_in[5];
  const float* Wq = (const float*)d_in[6];
  const float* bq = (const float*)d_in[7];
  const float* Wk = (const float*)d_in[8];
  const float* bk = (const float*)d_in[9];
  const float* Wv = (const float*)d_in[10];
  const float* bv = (const float*)d_in[11];
  const float* Wo = (const float*)d_in[12];
  const float* bo = (const float*)d_in[13];
  float* out = (float*)d_out;

  char* ws = (char*)d_ws;
  double* xs      = (double*)(ws + 0);
  int*   tk_idx   = (int*)  (ws + 131072);
  float* tk_gates = (float*)(ws + 131072 + 256);

  const size_t header = (size_t)1 << 20;
  const size_t XSB = (size_t)32 * SDSQ * 2;   // 16 MiB: one hi or lo slab of q/k/v
  const size_t WSB = (size_t)8  * SDSQ * 2;   // 4 MiB:  one hi or lo slab of a weight set
  u16t* qch = (u16t*)(ws + header + 0*XSB);
  u16t* qcl = (u16t*)(ws + header + 1*XSB);
  u16t* kh_ = (u16t*)(ws + header + 2*XSB);
  u16t* kl_ = (u16t*)(ws + header + 3*XSB);
  u16t* vh_ = (u16t*)(ws + header + 4*XSB);
  u16t* vl_ = (u16t*)(ws + header + 5*XSB);
  char* wbase = ws + header + 6*XSB;
  u16t* wqh = (u16t*)(wbase + 0*WSB);
  u16t* wql = (u16t*)(wbase + 1*WSB);
  u16t* wkh = (u16t*)(wbase + 2*WSB);
  u16t* wkl = (u16t*)(wbase + 3*WSB);
  u16t* wvh = (u16t*)(wbase + 4*WSB);
  u16t* wvl = (u16t*)(wbase + 5*WSB);
  u16t* woh = (u16t*)(wbase + 6*WSB);
  u16t* wol = (u16t*)(wbase + 7*WSB);
  char* bufbase = wbase + 8*WSB;

  const size_t slab = (size_t)SDSQ * 2;       // 0.5 MiB per pair per slab; 6 slabs/pair
  size_t used = (size_t)(bufbase - ws);
  size_t avail = (ws_size > used) ? (ws_size - used) : 0;
  int CH = (int)(avail / (6 * slab));
  CH &= ~1;
  if (CH > 64) CH = 64;
  if (CH < 2)  CH = 2;

  // pre-pass: split inputs, split+transpose weights
  k_cvt_x<<<dim3(8192), dim3(256), 0, stream>>>(q, qch, qcl, 1);
  k_cvt_x<<<dim3(8192), dim3(256), 0, stream>>>(k, kh_, kl_, 0);
  k_cvt_x<<<dim3(8192), dim3(256), 0, stream>>>(v, vh_, vl_, 0);
  k_cvt_w<<<dim3(8,8,8), dim3(256), 0, stream>>>(Wq, wqh, wql);
  k_cvt_w<<<dim3(8,8,8), dim3(256), 0, stream>>>(Wk, wkh, wkl);
  k_cvt_w<<<dim3(8,8,8), dim3(256), 0, stream>>>(Wv, wvh, wvl);
  k_cvt_w<<<dim3(8,8,8), dim3(256), 0, stream>>>(Wo, woh, wol);

  k_xs  <<<dim3(32,4), dim3(128), 0, stream>>>(q, xs);
  k_gate<<<dim3(1), dim3(256), 0, stream>>>(xs, wg, wn, tk_idx, tk_gates,
                                            out + (size_t)out_size - 1);

  for (int pair0 = 0; pair0 < 64; pair0 += CH){
    int cur = (64 - pair0 < CH) ? (64 - pair0) : CH;
    u16t* Qh  = (u16t*)bufbase;
    u16t* Ql  = Qh  + (size_t)CH * SDSQ;
    u16t* Kh  = Ql  + (size_t)CH * SDSQ;
    u16t* Kl  = Kh  + (size_t)CH * SDSQ;
    u16t* Vth = Kl  + (size_t)CH * SDSQ;
    u16t* Vtl = Vth + (size_t)CH * SDSQ;
    u16t* Ch = Qh;   // ctx in-place over Q slabs
    u16t* Cl = Ql;

    k_proj<<<dim3(4,4,cur*3), dim3(256), 0, stream>>>(
        qch,qcl, kh_,kl_, vh_,vl_, wqh,wql, wkh,wkl, wvh,wvl,
        bq,bk,bv, tk_idx, pair0, Qh,Ql, Kh,Kl, Vth,Vtl);
    k_attn<<<dim3(8,8,cur), dim3(256), 0, stream>>>(Qh,Ql, Kh,Kl, Vth,Vtl, Ch,Cl);
    k_out <<<dim3(8,8,cur/2), dim3(256), 0, stream>>>(Ch,Cl, woh,wol, bo, tk_idx, tk_gates,
                                                      pair0, out);
  }
}